// Round 12
// baseline (444.003 us; speedup 1.0000x reference)
//
#include <hip/hip_runtime.h>

#define N_NODES 6000
#define DEG_    16
#define N_EDGES (N_NODES*DEG_)
#define D_MODEL 256
#define D_MSG   64
#define D_FF    1024

typedef __bf16 bf16x8 __attribute__((ext_vector_type(8)));
typedef float floatx4 __attribute__((ext_vector_type(4)));

__device__ __forceinline__ float silu_f(float v) {
    return v * __builtin_amdgcn_rcpf(1.0f + __expf(-v));
}
__device__ __forceinline__ float b2f(unsigned short u) {
    union { unsigned int i; float f; } v; v.i = ((unsigned int)u) << 16; return v.f;
}
__device__ __forceinline__ unsigned short f2b(float f) {
    union { float f; unsigned int i; } v; v.f = f;
    unsigned int r = (v.i + 0x7FFFu + ((v.i >> 16) & 1u)) >> 16;
    return (unsigned short)r;
}

// ---------------- fused prep: weight cvt + embed + geom + Wcomb/wfc2/bias precompute ----------------
// Wcomb_l = [Wsrc_l;Wdst_l] @ W2_{l-1}  [128,1024]  (l = 1,2 0-indexed proj layers)
// bcomb_l = [Wsrc_l;Wdst_l] @ b2_{l-1} + [bsrc_l;bdst_l]
// wfc2    = Wfc @ W2_2 [1024];  out[0] = Wfc.b2_2 + bfc
#define WSRC_OFF 0
#define WDST_OFF 49152
#define WEDGE_OFF 98304
#define W1_OFF 147456
#define W2_OFF 344064
#define WTOTAL 1130496
#define CVT4_BLOCKS (WTOTAL/4/256)             // 1104
#define EMB4_BLOCKS (N_NODES*D_MODEL/4/256)    // 1500
#define GEOM_BLOCKS (N_EDGES/256)              // 375
#define WCOMB_BLOCKS 32
#define WFC2_BLOCKS 4
__global__ __launch_bounds__(256) void prep_kernel(
    const float* __restrict__ Wsrc, const float* __restrict__ bsrc,
    const float* __restrict__ Wdst, const float* __restrict__ bdst,
    const float* __restrict__ Wedge, const float* __restrict__ W1,
    const float* __restrict__ W2, const float* __restrict__ b2,
    const float* __restrict__ Wfc, const float* __restrict__ bfc,
    unsigned short* __restrict__ wbf_out,
    const int* __restrict__ an, const float* __restrict__ emb,
    unsigned short* __restrict__ x,
    const float* __restrict__ r, float* __restrict__ d, float* __restrict__ rhat,
    unsigned short* __restrict__ wcomb, float* __restrict__ bcomb,
    float* __restrict__ wfc2, float* __restrict__ out) {
    int b = blockIdx.x;
    int t = threadIdx.x;
    if (b < CVT4_BLOCKS) {
        int i = (b*256 + t) * 4;
        const float* sp;
        if      (i < WDST_OFF)  sp = Wsrc + i;
        else if (i < WEDGE_OFF) sp = Wdst + (i - WDST_OFF);
        else if (i < W1_OFF)    sp = Wedge + (i - WEDGE_OFF);
        else if (i < W2_OFF)    sp = W1 + (i - W1_OFF);
        else                    sp = W2 + (i - W2_OFF);
        float4 v = *(const float4*)sp;
        *(ushort4*)(wbf_out + i) = make_ushort4(f2b(v.x), f2b(v.y), f2b(v.z), f2b(v.w));
    } else if (b < CVT4_BLOCKS + EMB4_BLOCKS) {
        int i4 = (b - CVT4_BLOCKS)*256 + t;
        int node = i4 >> 6, c4 = i4 & 63;
        float4 v = *(const float4*)(emb + (size_t)an[node]*D_MODEL + c4*4);
        *(ushort4*)(x + (size_t)node*D_MODEL + c4*4) =
            make_ushort4(f2b(v.x), f2b(v.y), f2b(v.z), f2b(v.w));
    } else if (b < CVT4_BLOCKS + EMB4_BLOCKS + GEOM_BLOCKS) {
        int e = (b - CVT4_BLOCKS - EMB4_BLOCKS)*256 + t;
        float xx = r[e*3+0], yy = r[e*3+1], zz = r[e*3+2];
        float n = sqrtf(xx*xx + yy*yy + zz*zz);
        d[e] = n;
        float inv = 1.0f / n;
        *(float4*)(rhat + (size_t)e*4) = make_float4(xx*inv, yy*inv, zz*inv, 0.f);
    } else if (b < CVT4_BLOCKS + EMB4_BLOCKS + GEOM_BLOCKS + WCOMB_BLOCKS) {
        // Wcomb: 2 layers x 4 col-blocks x 4 row-blocks; 32 rows, 256 f-cols each
        int wb = b - (CVT4_BLOCKS + EMB4_BLOCKS + GEOM_BLOCKS);
        int lp = 1 + (wb >> 4);            // proj layer 1 or 2 (0-indexed)
        int sub = wb & 15;
        int r0 = (sub & 3) * 32;
        int f  = ((sub >> 2) << 8) + t;    // 0..1023
        const float* W2f = W2 + (size_t)(lp-1)*262144;
        float acc[32] = {};
        for (int k4 = 0; k4 < 64; ++k4) {
            float w0 = W2f[(size_t)(k4*4+0)*1024 + f];
            float w1 = W2f[(size_t)(k4*4+1)*1024 + f];
            float w2v = W2f[(size_t)(k4*4+2)*1024 + f];
            float w3 = W2f[(size_t)(k4*4+3)*1024 + f];
            #pragma unroll
            for (int rr = 0; rr < 32; ++rr) {
                int row = r0 + rr;
                const float* wmrow = (row < 64) ? (Wsrc + (size_t)lp*16384 + row*256)
                                                : (Wdst + (size_t)lp*16384 + (row-64)*256);
                float4 wm = *(const float4*)(wmrow + k4*4);
                acc[rr] += wm.x*w0 + wm.y*w1 + wm.z*w2v + wm.w*w3;
            }
        }
        #pragma unroll
        for (int rr = 0; rr < 32; ++rr)
            wcomb[(size_t)(lp-1)*131072 + (size_t)(r0+rr)*1024 + f] = f2b(acc[rr]);
    } else if (b < CVT4_BLOCKS + EMB4_BLOCKS + GEOM_BLOCKS + WCOMB_BLOCKS + WFC2_BLOCKS) {
        int wb = b - (CVT4_BLOCKS + EMB4_BLOCKS + GEOM_BLOCKS + WCOMB_BLOCKS);
        int c = wb*256 + t;
        const float* W2f = W2 + 2*262144;
        float acc = 0.f;
        for (int k = 0; k < 256; ++k) acc += Wfc[k] * W2f[(size_t)k*1024 + c];
        wfc2[c] = acc;
    } else {
        // bias block: bcomb for both proj layers + out init
        int lp = 1 + (t >> 7);
        int row = t & 127;
        const float* b2l = b2 + (lp-1)*256;
        const float* wmrow = (row < 64) ? (Wsrc + (size_t)lp*16384 + row*256)
                                        : (Wdst + (size_t)lp*16384 + (row-64)*256);
        float acc = 0.f;
        for (int c = 0; c < 256; ++c) acc += wmrow[c] * b2l[c];
        acc += (row < 64) ? bsrc[lp*64 + row] : bdst[lp*64 + (row-64)];
        bcomb[(lp-1)*128 + row] = acc;
        if (t == 0) {
            float bo = 0.f;
            const float* b23 = b2 + 2*256;
            for (int c = 0; c < 256; ++c) bo += Wfc[c] * b23[c];
            out[0] = bo + bfc[0];
        }
    }
}

// ---------------- eproj: [E,192] = RBF(d) @ Wedge^T + bedge, single pass ----------------
#define EPITCH 40
__global__ __launch_bounds__(256) void eproj_kernel(
    const unsigned short* __restrict__ Bw,  // [192,256] bf16 (3 layers stacked)
    const float* __restrict__ bias,         // [192]
    const float* __restrict__ dvec,         // [E]
    unsigned short* __restrict__ C) {       // [E,192]
    __shared__ __align__(16) unsigned short As[128*EPITCH];
    __shared__ __align__(16) unsigned short Bs[192*EPITCH];
    const int t = threadIdx.x;
    const int w = t >> 6, lane = t & 63, lr = lane & 15, lq = lane >> 4;
    const int m0 = blockIdx.x * 128;

    int arow[2], achk[2], brow[3], bchk[3];
    #pragma unroll
    for (int it = 0; it < 2; ++it) { int i = t + it*256; arow[it] = i >> 2; achk[it] = i & 3; }
    #pragma unroll
    for (int it = 0; it < 3; ++it) { int i = t + it*256; brow[it] = i >> 2; bchk[it] = i & 3; }

    float dv[2];
    dv[0] = dvec[m0 + arow[0]];
    dv[1] = dvec[m0 + arow[1]];

    floatx4 acc[2][12] = {};
    uint4 pb[3];
    #pragma unroll
    for (int it = 0; it < 3; ++it)
        pb[it] = *(const uint4*)(Bw + (size_t)brow[it]*256 + bchk[it]*8);

    const float gamma = 31.875f;
    const float step  = 8.0f / 255.0f;
    for (int k0 = 0; k0 < 256; k0 += 32) {
        #pragma unroll
        for (int it = 0; it < 2; ++it) {
            int kb = k0 + achk[it]*8;
            unsigned short h[8];
            #pragma unroll
            for (int j = 0; j < 8; ++j) {
                float tt = dv[it] - (float)(kb+j)*step;
                h[j] = f2b(__expf(-gamma*tt*tt));
            }
            *(uint4*)(&As[arow[it]*EPITCH + achk[it]*8]) = *(uint4*)h;
        }
        #pragma unroll
        for (int it = 0; it < 3; ++it)
            *(uint4*)(&Bs[brow[it]*EPITCH + bchk[it]*8]) = pb[it];
        __syncthreads();
        if (k0 + 32 < 256) {
            #pragma unroll
            for (int it = 0; it < 3; ++it)
                pb[it] = *(const uint4*)(Bw + (size_t)brow[it]*256 + (k0+32) + bchk[it]*8);
        }
        bf16x8 af0 = *(const bf16x8*)(&As[(w*32      + lr)*EPITCH + lq*8]);
        bf16x8 af1 = *(const bf16x8*)(&As[(w*32 + 16 + lr)*EPITCH + lq*8]);
        #pragma unroll
        for (int ns = 0; ns < 12; ++ns) {
            bf16x8 b = *(const bf16x8*)(&Bs[(ns*16 + lr)*EPITCH + lq*8]);
            acc[0][ns] = __builtin_amdgcn_mfma_f32_16x16x32_bf16(af0, b, acc[0][ns], 0,0,0);
            acc[1][ns] = __builtin_amdgcn_mfma_f32_16x16x32_bf16(af1, b, acc[1][ns], 0,0,0);
        }
        __syncthreads();
    }
    #pragma unroll
    for (int ns = 0; ns < 12; ++ns) {
        int bc = ns*16 + lr;
        float bv = bias[bc];
        #pragma unroll
        for (int fc = 0; fc < 2; ++fc) {
            #pragma unroll
            for (int rg = 0; rg < 4; ++rg) {
                int gm = m0 + w*32 + fc*16 + lq*4 + rg;
                C[(size_t)gm*192 + bc] = f2b(acc[fc][ns][rg] + bv);
            }
        }
    }
}

// ---------------- MFMA bf16 GEMM, software-pipelined staging ----------------
#define APITCH 40
template<int ACT, int DUALB, int TM>
__global__ __launch_bounds__(256) void mgemm(
    const unsigned short* __restrict__ A, int lda,
    const unsigned short* __restrict__ B1, const unsigned short* __restrict__ B2, int ldb,
    const float* __restrict__ bias1, const float* __restrict__ bias2,
    unsigned short* __restrict__ C, int ldc, int M, int K) {
    constexpr int WR = TM/4;
    constexpr int FC = WR/16;
    constexpr int NIT = TM/64;
    __shared__ __align__(16) unsigned short As[TM*APITCH];
    __shared__ __align__(16) unsigned short Bs[64*APITCH];
    const int t = threadIdx.x;
    const int w = t >> 6;
    const int lane = t & 63;
    const int lr = lane & 15;
    const int lq = lane >> 4;
    const int n0 = blockIdx.x * 64;
    const int m0 = blockIdx.y * TM;
    const unsigned short* B = B1;
    const float* bias = bias1;
    if (DUALB && blockIdx.x == 1) { B = B2; bias = bias2; }
    const unsigned short* Brow = DUALB ? B : (B + (size_t)n0*ldb);

    int arow[NIT], achk[NIT];
    #pragma unroll
    for (int it = 0; it < NIT; ++it) { int i = t + it*256; arow[it] = i >> 2; achk[it] = i & 3; }
    const int brow = t >> 2, bchk = t & 3;

    floatx4 acc[FC][4] = {};
    uint4 pa[NIT], pb;

    #pragma unroll
    for (int it = 0; it < NIT; ++it) {
        int gm = m0 + arow[it];
        pa[it] = (gm < M) ? *(const uint4*)(A + (size_t)gm*lda + achk[it]*8) : make_uint4(0,0,0,0);
    }
    pb = *(const uint4*)(Brow + (size_t)brow*ldb + bchk*8);

    for (int k0 = 0; k0 < K; k0 += 32) {
        #pragma unroll
        for (int it = 0; it < NIT; ++it)
            *(uint4*)(&As[arow[it]*APITCH + achk[it]*8]) = pa[it];
        *(uint4*)(&Bs[brow*APITCH + bchk*8]) = pb;
        __syncthreads();
        if (k0 + 32 < K) {
            int kn = k0 + 32;
            #pragma unroll
            for (int it = 0; it < NIT; ++it) {
                int gm = m0 + arow[it];
                pa[it] = (gm < M) ? *(const uint4*)(A + (size_t)gm*lda + kn + achk[it]*8) : make_uint4(0,0,0,0);
            }
            pb = *(const uint4*)(Brow + (size_t)brow*ldb + kn + bchk*8);
        }
        bf16x8 af[FC], bfr[4];
        #pragma unroll
        for (int fc = 0; fc < FC; ++fc)
            af[fc] = *(const bf16x8*)(&As[(w*WR + fc*16 + lr)*APITCH + lq*8]);
        #pragma unroll
        for (int ns = 0; ns < 4; ++ns)
            bfr[ns] = *(const bf16x8*)(&Bs[(ns*16 + lr)*APITCH + lq*8]);
        #pragma unroll
        for (int ns = 0; ns < 4; ++ns)
            #pragma unroll
            for (int fc = 0; fc < FC; ++fc)
                acc[fc][ns] = __builtin_amdgcn_mfma_f32_16x16x32_bf16(af[fc], bfr[ns], acc[fc][ns], 0,0,0);
        __syncthreads();
    }
    #pragma unroll
    for (int ns = 0; ns < 4; ++ns) {
        int bc = ns*16 + lr;
        float bv = bias[DUALB ? bc : (n0 + bc)];
        #pragma unroll
        for (int fc = 0; fc < FC; ++fc) {
            #pragma unroll
            for (int rg = 0; rg < 4; ++rg) {
                int gm = m0 + w*WR + fc*16 + lq*4 + rg;
                if (gm < M) {
                    float v = acc[fc][ns][rg] + bv;
                    if (ACT) v = silu_f(v);
                    C[(size_t)gm*ldc + n0 + bc] = f2b(v);
                }
            }
        }
    }
}

// ---------------- angle attention, TWO nodes per block ----------------
__global__ __launch_bounds__(256) void angle_kernel(
    const unsigned short* __restrict__ xjxi,
    const unsigned short* __restrict__ eproj,
    const float* __restrict__ rhat,
    const int*   __restrict__ src,
    const float* __restrict__ attn,
    unsigned short* __restrict__ xn) {
    __shared__ __align__(16) float s_xij[2][16][68];
    __shared__ float s_rhat[2][16][4];
    __shared__ float s_logit[2][16][17];
    __shared__ float s_e[2][16][17];
    __shared__ float s_m[2][16], s_zi[2][16];
    __shared__ float s_w[2][16];
    const int t = threadIdx.x;
    const int h = t >> 7, tt = t & 127;
    const int node = blockIdx.x*2 + h;

    if (tt < 16) {
        float4 rv = *(const float4*)(rhat + (size_t)(node*DEG_ + tt)*4);
        s_rhat[h][tt][0] = rv.x; s_rhat[h][tt][1] = rv.y; s_rhat[h][tt][2] = rv.z; s_rhat[h][tt][3] = 0.f;
        s_e[h][tt][tt] = 0.f;
    }
    {
        int p = tt >> 3, c8 = tt & 7;
        int e = node*DEG_ + p;
        int se = src[e];
        uint4 aj = *(const uint4*)(xjxi + (size_t)se*128 + c8*8);
        uint4 ai = *(const uint4*)(xjxi + (size_t)node*128 + 64 + c8*8);
        uint4 ae = *(const uint4*)(eproj + (size_t)e*192 + c8*8);
        const unsigned short* pj = (const unsigned short*)&aj;
        const unsigned short* pi = (const unsigned short*)&ai;
        const unsigned short* pe = (const unsigned short*)&ae;
        #pragma unroll
        for (int j = 0; j < 8; ++j)
            s_xij[h][p][c8*8 + j] = b2f(pj[j]) + b2f(pi[j]) + b2f(pe[j]);
    }
    __syncthreads();
    int pp = 0, qq = 0;
    float lg = 0.f;
    if (tt < 120) {
        pp = (int)((1.0f + sqrtf(8.0f*(float)tt + 1.0f)) * 0.5f);
        qq = tt - ((pp*(pp-1)) >> 1);
        float c = s_rhat[h][pp][0]*s_rhat[h][qq][0] + s_rhat[h][pp][1]*s_rhat[h][qq][1]
                + s_rhat[h][pp][2]*s_rhat[h][qq][2];
        c = fminf(fmaxf(c, -0.999999f), 0.999999f);
        float c2  = 2.0f * c;
        float tk0 = 1.0f;
        float tk1 = c;
        float acc = 0.f;
        const float* xp = &s_xij[h][pp][0];
        const float* xq = &s_xij[h][qq][0];
        #pragma unroll
        for (int k0 = 0; k0 < 64; k0 += 4) {
            float4 xp4 = *(const float4*)(xp + k0);
            float4 xq4 = *(const float4*)(xq + k0);
            float a0 = attn[k0+0], a1 = attn[k0+1], a2 = attn[k0+2], a3 = attn[k0+3];
            float v0 = tk0 + xp4.x + xq4.x;
            acc = fmaf(a0, silu_f(v0), acc);
            { float tn2 = c2*tk1 - tk0; tk0 = tk1; tk1 = tn2; }
            float v1 = tk0 + xp4.y + xq4.y;
            acc = fmaf(a1, silu_f(v1), acc);
            { float tn2 = c2*tk1 - tk0; tk0 = tk1; tk1 = tn2; }
            float v2 = tk0 + xp4.z + xq4.z;
            acc = fmaf(a2, silu_f(v2), acc);
            { float tn2 = c2*tk1 - tk0; tk0 = tk1; tk1 = tn2; }
            float v3 = tk0 + xp4.w + xq4.w;
            acc = fmaf(a3, silu_f(v3), acc);
            { float tn2 = c2*tk1 - tk0; tk0 = tk1; tk1 = tn2; }
        }
        lg = acc;
        s_logit[h][pp][qq] = acc;
        s_logit[h][qq][pp] = acc;
    }
    __syncthreads();
    if (tt < 16) {
        int q = tt;
        float mx = -1e30f;
        #pragma unroll
        for (int p = 0; p < 16; ++p) if (p != q) mx = fmaxf(mx, s_logit[h][p][q]);
        s_m[h][q] = mx;
    }
    __syncthreads();
    if (tt < 120) {
        s_e[h][pp][qq] = __expf(lg - s_m[h][qq]);
        s_e[h][qq][pp] = __expf(lg - s_m[h][pp]);
    }
    __syncthreads();
    if (tt < 16) {
        int q = tt;
        float z = 0.f;
        #pragma unroll
        for (int p = 0; p < 16; ++p) z += s_e[h][p][q];
        s_zi[h][q] = __builtin_amdgcn_rcpf(z);
    }
    __syncthreads();
    if (tt < 16) {
        int p = tt;
        float sw = 0.f;
        #pragma unroll
        for (int q = 0; q < 16; ++q) sw += s_e[h][p][q] * s_zi[h][q];
        s_w[h][p] = sw;
    }
    __syncthreads();
    if (tt < 64) {
        float acc = 0.f;
        #pragma unroll
        for (int p = 0; p < 16; ++p) acc += s_w[h][p] * s_xij[h][p][tt];
        xn[(size_t)node*64 + tt] = f2b(acc);
    }
}

// ---------------- final: out += mean_i (h3[i] . wfc2)   (out pre-set to bout by prep) ----------------
__global__ __launch_bounds__(256) void reduce2_kernel(const unsigned short* __restrict__ hh,
    const float* __restrict__ wfc2, float* __restrict__ out) {
    __shared__ float s[256];
    int t = threadIdx.x;
    float w0 = wfc2[t*4+0], w1 = wfc2[t*4+1], w2 = wfc2[t*4+2], w3 = wfc2[t*4+3];
    float local = 0.f;
    for (int i = blockIdx.x; i < N_NODES; i += gridDim.x) {
        ushort4 hv = *(const ushort4*)(hh + (size_t)i*D_FF + t*4);
        local += b2f(hv.x)*w0 + b2f(hv.y)*w1 + b2f(hv.z)*w2 + b2f(hv.w)*w3;
    }
    s[t] = local; __syncthreads();
    for (int off = 128; off > 0; off >>= 1) {
        if (t < off) s[t] += s[t+off];
        __syncthreads();
    }
    if (t == 0) atomicAdd(out, s[0] * (1.0f/(float)N_NODES));
}

extern "C" void kernel_launch(void* const* d_in, const int* in_sizes, int n_in,
                              void* d_out, int out_size, void* d_ws, size_t ws_size,
                              hipStream_t stream) {
    (void)in_sizes; (void)n_in; (void)out_size; (void)ws_size;
    const float* r    = (const float*)d_in[0];
    const int*   an   = (const int*)  d_in[1];
    const int*   src  = (const int*)  d_in[2];
    const float* emb  = (const float*)d_in[6];
    const float* Wsrc = (const float*)d_in[7];
    const float* bsrc = (const float*)d_in[8];
    const float* Wdst = (const float*)d_in[9];
    const float* bdst = (const float*)d_in[10];
    const float* Wedge= (const float*)d_in[11];
    const float* bedge= (const float*)d_in[12];
    const float* attn = (const float*)d_in[13];
    const float* W1   = (const float*)d_in[14];
    const float* b1   = (const float*)d_in[15];
    const float* W2   = (const float*)d_in[16];
    const float* b2   = (const float*)d_in[17];
    const float* Wfc  = (const float*)d_in[18];
    const float* bfc  = (const float*)d_in[19];

    char* ws = (char*)d_ws;
    float* d_d              = (float*)(ws);                    // 384000 B
    float* d_rhat           = (float*)(ws + 384000);           // 1536000 B
    unsigned short* wbf     = (unsigned short*)(ws + 1920000); // 2260992 B
    unsigned short* d_x     = (unsigned short*)(ws + 4180992); // 3072000 B
    unsigned short* d_xjxi  = (unsigned short*)(ws + 7252992); // 1536000 B
    unsigned short* d_eproj = (unsigned short*)(ws + 8788992); // 36864000 B
    unsigned short* d_xn    = (unsigned short*)(ws + 45652992);// 768000 B
    unsigned short* d_h     = (unsigned short*)(ws + 46420992);// 12288000 B
    unsigned short* d_wcomb = (unsigned short*)(ws + 58708992);// 524288 B
    float* d_bcomb          = (float*)(ws + 59233280);         // 1024 B
    float* d_wfc2           = (float*)(ws + 59234304);         // 4096 B
    float* out = (float*)d_out;

    unsigned short* wsrc_bf  = wbf + WSRC_OFF;
    unsigned short* wdst_bf  = wbf + WDST_OFF;
    unsigned short* wedge_bf = wbf + WEDGE_OFF;
    unsigned short* w1_bf    = wbf + W1_OFF;

    prep_kernel<<<CVT4_BLOCKS + EMB4_BLOCKS + GEOM_BLOCKS + WCOMB_BLOCKS + WFC2_BLOCKS + 1,
                  256, 0, stream>>>(
        Wsrc, bsrc, Wdst, bdst, Wedge, W1, W2, b2, Wfc, bfc,
        wbf, an, emb, d_x, r, d_d, d_rhat, d_wcomb, d_bcomb, d_wfc2, out);
    eproj_kernel<<<750, 256, 0, stream>>>(wedge_bf, bedge, d_d, d_eproj);

    // ---- layer 0 ----
    mgemm<0,1,64><<<dim3(2,94), 256, 0, stream>>>(
        d_x, 256, wsrc_bf, wdst_bf, 256,
        bsrc, bdst, d_xjxi, 128, N_NODES, 256);
    angle_kernel<<<N_NODES/2, 256, 0, stream>>>(
        d_xjxi, d_eproj, d_rhat, src, attn, d_xn);
    mgemm<1,0,64><<<dim3(16,94), 256, 0, stream>>>(
        d_xn, 64, w1_bf, (const unsigned short*)nullptr, 64,
        b1, (const float*)nullptr, d_h, D_FF, N_NODES, 64);
    // fused FFN2+proj: xjxi(1) = h @ Wcomb1^T + bcomb1
    mgemm<0,0,64><<<dim3(2,94), 256, 0, stream>>>(
        d_h, 1024, d_wcomb, (const unsigned short*)nullptr, 1024,
        d_bcomb, (const float*)nullptr, d_xjxi, 128, N_NODES, 1024);

    // ---- layer 1 ----
    angle_kernel<<<N_NODES/2, 256, 0, stream>>>(
        d_xjxi, d_eproj + 64, d_rhat, src, attn + 64, d_xn);
    mgemm<1,0,64><<<dim3(16,94), 256, 0, stream>>>(
        d_xn, 64, w1_bf + 65536, (const unsigned short*)nullptr, 64,
        b1 + 1024, (const float*)nullptr, d_h, D_FF, N_NODES, 64);
    mgemm<0,0,64><<<dim3(2,94), 256, 0, stream>>>(
        d_h, 1024, d_wcomb + 131072, (const unsigned short*)nullptr, 1024,
        d_bcomb + 128, (const float*)nullptr, d_xjxi, 128, N_NODES, 1024);

    // ---- layer 2 ----
    angle_kernel<<<N_NODES/2, 256, 0, stream>>>(
        d_xjxi, d_eproj + 128, d_rhat, src, attn + 128, d_xn);
    mgemm<1,0,64><<<dim3(16,94), 256, 0, stream>>>(
        d_xn, 64, w1_bf + 131072, (const unsigned short*)nullptr, 64,
        b1 + 2048, (const float*)nullptr, d_h, D_FF, N_NODES, 64);
    // head: out = bout + mean(h @ wfc2)
    reduce2_kernel<<<48, 256, 0, stream>>>(d_h, d_wfc2, out);
}

// Round 13
// 327.806 us; speedup vs baseline: 1.3545x; 1.3545x over previous
//
#include <hip/hip_runtime.h>

#define N_NODES 6000
#define DEG_    16
#define N_EDGES (N_NODES*DEG_)
#define D_MODEL 256
#define D_MSG   64
#define D_FF    1024

typedef __bf16 bf16x8 __attribute__((ext_vector_type(8)));
typedef float floatx4 __attribute__((ext_vector_type(4)));

__device__ __forceinline__ float silu_f(float v) {
    return v * __builtin_amdgcn_rcpf(1.0f + __expf(-v));
}
__device__ __forceinline__ float b2f(unsigned short u) {
    union { unsigned int i; float f; } v; v.i = ((unsigned int)u) << 16; return v.f;
}
__device__ __forceinline__ unsigned short f2b(float f) {
    union { float f; unsigned int i; } v; v.f = f;
    unsigned int r = (v.i + 0x7FFFu + ((v.i >> 16) & 1u)) >> 16;
    return (unsigned short)r;
}

// ---------------- fused prep: weight cvt + embed + geom + Wcomb/wfc2/bias precompute ----------------
// Wcomb_l = [Wsrc_l;Wdst_l] @ W2_{l-1}  [128,1024]; one block per (layer,row) for parallelism
// bcomb_l = [Wsrc_l;Wdst_l] @ b2_{l-1} + [bsrc_l;bdst_l]
// wfc2    = Wfc @ W2_2 [1024];  out[0] = Wfc.b2_2 + bfc
#define WSRC_OFF 0
#define WDST_OFF 49152
#define WEDGE_OFF 98304
#define W1_OFF 147456
#define W2_OFF 344064
#define WTOTAL 1130496
#define CVT4_BLOCKS (WTOTAL/4/256)             // 1104
#define EMB4_BLOCKS (N_NODES*D_MODEL/4/256)    // 1500
#define GEOM_BLOCKS (N_EDGES/256)              // 375
#define WCOMB_BLOCKS 256                       // 2 layers x 128 rows
#define WFC2_BLOCKS 4
__global__ __launch_bounds__(256) void prep_kernel(
    const float* __restrict__ Wsrc, const float* __restrict__ bsrc,
    const float* __restrict__ Wdst, const float* __restrict__ bdst,
    const float* __restrict__ Wedge, const float* __restrict__ W1,
    const float* __restrict__ W2, const float* __restrict__ b2,
    const float* __restrict__ Wfc, const float* __restrict__ bfc,
    unsigned short* __restrict__ wbf_out,
    const int* __restrict__ an, const float* __restrict__ emb,
    unsigned short* __restrict__ x,
    const float* __restrict__ r, float* __restrict__ d, float* __restrict__ rhat,
    unsigned short* __restrict__ wcomb, float* __restrict__ bcomb,
    float* __restrict__ wfc2, float* __restrict__ out) {
    int b = blockIdx.x;
    int t = threadIdx.x;
    if (b < CVT4_BLOCKS) {
        int i = (b*256 + t) * 4;
        const float* sp;
        if      (i < WDST_OFF)  sp = Wsrc + i;
        else if (i < WEDGE_OFF) sp = Wdst + (i - WDST_OFF);
        else if (i < W1_OFF)    sp = Wedge + (i - WEDGE_OFF);
        else if (i < W2_OFF)    sp = W1 + (i - W1_OFF);
        else                    sp = W2 + (i - W2_OFF);
        float4 v = *(const float4*)sp;
        *(ushort4*)(wbf_out + i) = make_ushort4(f2b(v.x), f2b(v.y), f2b(v.z), f2b(v.w));
    } else if (b < CVT4_BLOCKS + EMB4_BLOCKS) {
        int i4 = (b - CVT4_BLOCKS)*256 + t;
        int node = i4 >> 6, c4 = i4 & 63;
        float4 v = *(const float4*)(emb + (size_t)an[node]*D_MODEL + c4*4);
        *(ushort4*)(x + (size_t)node*D_MODEL + c4*4) =
            make_ushort4(f2b(v.x), f2b(v.y), f2b(v.z), f2b(v.w));
    } else if (b < CVT4_BLOCKS + EMB4_BLOCKS + GEOM_BLOCKS) {
        int e = (b - CVT4_BLOCKS - EMB4_BLOCKS)*256 + t;
        float xx = r[e*3+0], yy = r[e*3+1], zz = r[e*3+2];
        float n = sqrtf(xx*xx + yy*yy + zz*zz);
        d[e] = n;
        float inv = 1.0f / n;
        *(float4*)(rhat + (size_t)e*4) = make_float4(xx*inv, yy*inv, zz*inv, 0.f);
    } else if (b < CVT4_BLOCKS + EMB4_BLOCKS + GEOM_BLOCKS + WCOMB_BLOCKS) {
        // one block per (layer, row): t owns cols t*4..t*4+3
        int wb = b - (CVT4_BLOCKS + EMB4_BLOCKS + GEOM_BLOCKS);
        int lp  = 1 + (wb >> 7);           // proj layer 1 or 2 (0-indexed)
        int row = wb & 127;
        const float* wmrow = (row < 64) ? (Wsrc + (size_t)lp*16384 + row*256)
                                        : (Wdst + (size_t)lp*16384 + (row-64)*256);
        const float* W2f = W2 + (size_t)(lp-1)*262144;
        float a0 = 0.f, a1 = 0.f, a2 = 0.f, a3 = 0.f;
        int f = t*4;
        #pragma unroll 4
        for (int c = 0; c < 256; ++c) {
            float wm = wmrow[c];           // wave-uniform -> scalar load
            float4 w2v = *(const float4*)(W2f + (size_t)c*1024 + f);
            a0 = fmaf(wm, w2v.x, a0);
            a1 = fmaf(wm, w2v.y, a1);
            a2 = fmaf(wm, w2v.z, a2);
            a3 = fmaf(wm, w2v.w, a3);
        }
        *(ushort4*)(wcomb + (size_t)(lp-1)*131072 + (size_t)row*1024 + f) =
            make_ushort4(f2b(a0), f2b(a1), f2b(a2), f2b(a3));
    } else if (b < CVT4_BLOCKS + EMB4_BLOCKS + GEOM_BLOCKS + WCOMB_BLOCKS + WFC2_BLOCKS) {
        int wb = b - (CVT4_BLOCKS + EMB4_BLOCKS + GEOM_BLOCKS + WCOMB_BLOCKS);
        int c = wb*256 + t;
        const float* W2f = W2 + 2*262144;
        float acc = 0.f;
        for (int k = 0; k < 256; ++k) acc += Wfc[k] * W2f[(size_t)k*1024 + c];
        wfc2[c] = acc;
    } else {
        // bias block: bcomb for both proj layers + out init
        int lp = 1 + (t >> 7);
        int row = t & 127;
        const float* b2l = b2 + (lp-1)*256;
        const float* wmrow = (row < 64) ? (Wsrc + (size_t)lp*16384 + row*256)
                                        : (Wdst + (size_t)lp*16384 + (row-64)*256);
        float acc = 0.f;
        for (int c = 0; c < 256; ++c) acc += wmrow[c] * b2l[c];
        acc += (row < 64) ? bsrc[lp*64 + row] : bdst[lp*64 + (row-64)];
        bcomb[(lp-1)*128 + row] = acc;
        if (t == 0) {
            float bo = 0.f;
            const float* b23 = b2 + 2*256;
            for (int c = 0; c < 256; ++c) bo += Wfc[c] * b23[c];
            out[0] = bo + bfc[0];
        }
    }
}

// ---------------- eproj: [E,192] = RBF(d) @ Wedge^T + bedge, single pass ----------------
#define EPITCH 40
__global__ __launch_bounds__(256) void eproj_kernel(
    const unsigned short* __restrict__ Bw,  // [192,256] bf16 (3 layers stacked)
    const float* __restrict__ bias,         // [192]
    const float* __restrict__ dvec,         // [E]
    unsigned short* __restrict__ C) {       // [E,192]
    __shared__ __align__(16) unsigned short As[128*EPITCH];
    __shared__ __align__(16) unsigned short Bs[192*EPITCH];
    const int t = threadIdx.x;
    const int w = t >> 6, lane = t & 63, lr = lane & 15, lq = lane >> 4;
    const int m0 = blockIdx.x * 128;

    int arow[2], achk[2], brow[3], bchk[3];
    #pragma unroll
    for (int it = 0; it < 2; ++it) { int i = t + it*256; arow[it] = i >> 2; achk[it] = i & 3; }
    #pragma unroll
    for (int it = 0; it < 3; ++it) { int i = t + it*256; brow[it] = i >> 2; bchk[it] = i & 3; }

    float dv[2];
    dv[0] = dvec[m0 + arow[0]];
    dv[1] = dvec[m0 + arow[1]];

    floatx4 acc[2][12] = {};
    uint4 pb[3];
    #pragma unroll
    for (int it = 0; it < 3; ++it)
        pb[it] = *(const uint4*)(Bw + (size_t)brow[it]*256 + bchk[it]*8);

    const float gamma = 31.875f;
    const float step  = 8.0f / 255.0f;
    for (int k0 = 0; k0 < 256; k0 += 32) {
        #pragma unroll
        for (int it = 0; it < 2; ++it) {
            int kb = k0 + achk[it]*8;
            unsigned short h[8];
            #pragma unroll
            for (int j = 0; j < 8; ++j) {
                float tt = dv[it] - (float)(kb+j)*step;
                h[j] = f2b(__expf(-gamma*tt*tt));
            }
            *(uint4*)(&As[arow[it]*EPITCH + achk[it]*8]) = *(uint4*)h;
        }
        #pragma unroll
        for (int it = 0; it < 3; ++it)
            *(uint4*)(&Bs[brow[it]*EPITCH + bchk[it]*8]) = pb[it];
        __syncthreads();
        if (k0 + 32 < 256) {
            #pragma unroll
            for (int it = 0; it < 3; ++it)
                pb[it] = *(const uint4*)(Bw + (size_t)brow[it]*256 + (k0+32) + bchk[it]*8);
        }
        bf16x8 af0 = *(const bf16x8*)(&As[(w*32      + lr)*EPITCH + lq*8]);
        bf16x8 af1 = *(const bf16x8*)(&As[(w*32 + 16 + lr)*EPITCH + lq*8]);
        #pragma unroll
        for (int ns = 0; ns < 12; ++ns) {
            bf16x8 b = *(const bf16x8*)(&Bs[(ns*16 + lr)*EPITCH + lq*8]);
            acc[0][ns] = __builtin_amdgcn_mfma_f32_16x16x32_bf16(af0, b, acc[0][ns], 0,0,0);
            acc[1][ns] = __builtin_amdgcn_mfma_f32_16x16x32_bf16(af1, b, acc[1][ns], 0,0,0);
        }
        __syncthreads();
    }
    #pragma unroll
    for (int ns = 0; ns < 12; ++ns) {
        int bc = ns*16 + lr;
        float bv = bias[bc];
        #pragma unroll
        for (int fc = 0; fc < 2; ++fc) {
            #pragma unroll
            for (int rg = 0; rg < 4; ++rg) {
                int gm = m0 + w*32 + fc*16 + lq*4 + rg;
                C[(size_t)gm*192 + bc] = f2b(acc[fc][ns][rg] + bv);
            }
        }
    }
}

// ---------------- MFMA bf16 GEMM, software-pipelined staging ----------------
#define APITCH 40
template<int ACT, int DUALB, int TM>
__global__ __launch_bounds__(256) void mgemm(
    const unsigned short* __restrict__ A, int lda,
    const unsigned short* __restrict__ B1, const unsigned short* __restrict__ B2, int ldb,
    const float* __restrict__ bias1, const float* __restrict__ bias2,
    unsigned short* __restrict__ C, int ldc, int M, int K) {
    constexpr int WR = TM/4;
    constexpr int FC = WR/16;
    constexpr int NIT = TM/64;
    __shared__ __align__(16) unsigned short As[TM*APITCH];
    __shared__ __align__(16) unsigned short Bs[64*APITCH];
    const int t = threadIdx.x;
    const int w = t >> 6;
    const int lane = t & 63;
    const int lr = lane & 15;
    const int lq = lane >> 4;
    const int n0 = blockIdx.x * 64;
    const int m0 = blockIdx.y * TM;
    const unsigned short* B = B1;
    const float* bias = bias1;
    if (DUALB && blockIdx.x == 1) { B = B2; bias = bias2; }
    const unsigned short* Brow = DUALB ? B : (B + (size_t)n0*ldb);

    int arow[NIT], achk[NIT];
    #pragma unroll
    for (int it = 0; it < NIT; ++it) { int i = t + it*256; arow[it] = i >> 2; achk[it] = i & 3; }
    const int brow = t >> 2, bchk = t & 3;

    floatx4 acc[FC][4] = {};
    uint4 pa[NIT], pb;

    #pragma unroll
    for (int it = 0; it < NIT; ++it) {
        int gm = m0 + arow[it];
        pa[it] = (gm < M) ? *(const uint4*)(A + (size_t)gm*lda + achk[it]*8) : make_uint4(0,0,0,0);
    }
    pb = *(const uint4*)(Brow + (size_t)brow*ldb + bchk*8);

    for (int k0 = 0; k0 < K; k0 += 32) {
        #pragma unroll
        for (int it = 0; it < NIT; ++it)
            *(uint4*)(&As[arow[it]*APITCH + achk[it]*8]) = pa[it];
        *(uint4*)(&Bs[brow*APITCH + bchk*8]) = pb;
        __syncthreads();
        if (k0 + 32 < K) {
            int kn = k0 + 32;
            #pragma unroll
            for (int it = 0; it < NIT; ++it) {
                int gm = m0 + arow[it];
                pa[it] = (gm < M) ? *(const uint4*)(A + (size_t)gm*lda + kn + achk[it]*8) : make_uint4(0,0,0,0);
            }
            pb = *(const uint4*)(Brow + (size_t)brow*ldb + kn + bchk*8);
        }
        bf16x8 af[FC], bfr[4];
        #pragma unroll
        for (int fc = 0; fc < FC; ++fc)
            af[fc] = *(const bf16x8*)(&As[(w*WR + fc*16 + lr)*APITCH + lq*8]);
        #pragma unroll
        for (int ns = 0; ns < 4; ++ns)
            bfr[ns] = *(const bf16x8*)(&Bs[(ns*16 + lr)*APITCH + lq*8]);
        #pragma unroll
        for (int ns = 0; ns < 4; ++ns)
            #pragma unroll
            for (int fc = 0; fc < FC; ++fc)
                acc[fc][ns] = __builtin_amdgcn_mfma_f32_16x16x32_bf16(af[fc], bfr[ns], acc[fc][ns], 0,0,0);
        __syncthreads();
    }
    #pragma unroll
    for (int ns = 0; ns < 4; ++ns) {
        int bc = ns*16 + lr;
        float bv = bias[DUALB ? bc : (n0 + bc)];
        #pragma unroll
        for (int fc = 0; fc < FC; ++fc) {
            #pragma unroll
            for (int rg = 0; rg < 4; ++rg) {
                int gm = m0 + w*WR + fc*16 + lq*4 + rg;
                if (gm < M) {
                    float v = acc[fc][ns][rg] + bv;
                    if (ACT) v = silu_f(v);
                    C[(size_t)gm*ldc + n0 + bc] = f2b(v);
                }
            }
        }
    }
}

// ---------------- angle attention, TWO nodes per block ----------------
__global__ __launch_bounds__(256) void angle_kernel(
    const unsigned short* __restrict__ xjxi,
    const unsigned short* __restrict__ eproj,
    const float* __restrict__ rhat,
    const int*   __restrict__ src,
    const float* __restrict__ attn,
    unsigned short* __restrict__ xn) {
    __shared__ __align__(16) float s_xij[2][16][68];
    __shared__ float s_rhat[2][16][4];
    __shared__ float s_logit[2][16][17];
    __shared__ float s_e[2][16][17];
    __shared__ float s_m[2][16], s_zi[2][16];
    __shared__ float s_w[2][16];
    const int t = threadIdx.x;
    const int h = t >> 7, tt = t & 127;
    const int node = blockIdx.x*2 + h;

    if (tt < 16) {
        float4 rv = *(const float4*)(rhat + (size_t)(node*DEG_ + tt)*4);
        s_rhat[h][tt][0] = rv.x; s_rhat[h][tt][1] = rv.y; s_rhat[h][tt][2] = rv.z; s_rhat[h][tt][3] = 0.f;
        s_e[h][tt][tt] = 0.f;
    }
    {
        int p = tt >> 3, c8 = tt & 7;
        int e = node*DEG_ + p;
        int se = src[e];
        uint4 aj = *(const uint4*)(xjxi + (size_t)se*128 + c8*8);
        uint4 ai = *(const uint4*)(xjxi + (size_t)node*128 + 64 + c8*8);
        uint4 ae = *(const uint4*)(eproj + (size_t)e*192 + c8*8);
        const unsigned short* pj = (const unsigned short*)&aj;
        const unsigned short* pi = (const unsigned short*)&ai;
        const unsigned short* pe = (const unsigned short*)&ae;
        #pragma unroll
        for (int j = 0; j < 8; ++j)
            s_xij[h][p][c8*8 + j] = b2f(pj[j]) + b2f(pi[j]) + b2f(pe[j]);
    }
    __syncthreads();
    int pp = 0, qq = 0;
    float lg = 0.f;
    if (tt < 120) {
        pp = (int)((1.0f + sqrtf(8.0f*(float)tt + 1.0f)) * 0.5f);
        qq = tt - ((pp*(pp-1)) >> 1);
        float c = s_rhat[h][pp][0]*s_rhat[h][qq][0] + s_rhat[h][pp][1]*s_rhat[h][qq][1]
                + s_rhat[h][pp][2]*s_rhat[h][qq][2];
        c = fminf(fmaxf(c, -0.999999f), 0.999999f);
        float c2  = 2.0f * c;
        float tk0 = 1.0f;
        float tk1 = c;
        float acc = 0.f;
        const float* xp = &s_xij[h][pp][0];
        const float* xq = &s_xij[h][qq][0];
        #pragma unroll
        for (int k0 = 0; k0 < 64; k0 += 4) {
            float4 xp4 = *(const float4*)(xp + k0);
            float4 xq4 = *(const float4*)(xq + k0);
            float a0 = attn[k0+0], a1 = attn[k0+1], a2 = attn[k0+2], a3 = attn[k0+3];
            float v0 = tk0 + xp4.x + xq4.x;
            acc = fmaf(a0, silu_f(v0), acc);
            { float tn2 = c2*tk1 - tk0; tk0 = tk1; tk1 = tn2; }
            float v1 = tk0 + xp4.y + xq4.y;
            acc = fmaf(a1, silu_f(v1), acc);
            { float tn2 = c2*tk1 - tk0; tk0 = tk1; tk1 = tn2; }
            float v2 = tk0 + xp4.z + xq4.z;
            acc = fmaf(a2, silu_f(v2), acc);
            { float tn2 = c2*tk1 - tk0; tk0 = tk1; tk1 = tn2; }
            float v3 = tk0 + xp4.w + xq4.w;
            acc = fmaf(a3, silu_f(v3), acc);
            { float tn2 = c2*tk1 - tk0; tk0 = tk1; tk1 = tn2; }
        }
        lg = acc;
        s_logit[h][pp][qq] = acc;
        s_logit[h][qq][pp] = acc;
    }
    __syncthreads();
    if (tt < 16) {
        int q = tt;
        float mx = -1e30f;
        #pragma unroll
        for (int p = 0; p < 16; ++p) if (p != q) mx = fmaxf(mx, s_logit[h][p][q]);
        s_m[h][q] = mx;
    }
    __syncthreads();
    if (tt < 120) {
        s_e[h][pp][qq] = __expf(lg - s_m[h][qq]);
        s_e[h][qq][pp] = __expf(lg - s_m[h][pp]);
    }
    __syncthreads();
    if (tt < 16) {
        int q = tt;
        float z = 0.f;
        #pragma unroll
        for (int p = 0; p < 16; ++p) z += s_e[h][p][q];
        s_zi[h][q] = __builtin_amdgcn_rcpf(z);
    }
    __syncthreads();
    if (tt < 16) {
        int p = tt;
        float sw = 0.f;
        #pragma unroll
        for (int q = 0; q < 16; ++q) sw += s_e[h][p][q] * s_zi[h][q];
        s_w[h][p] = sw;
    }
    __syncthreads();
    if (tt < 64) {
        float acc = 0.f;
        #pragma unroll
        for (int p = 0; p < 16; ++p) acc += s_w[h][p] * s_xij[h][p][tt];
        xn[(size_t)node*64 + tt] = f2b(acc);
    }
}

// ---------------- final: out += mean_i (h3[i] . wfc2)   (out pre-set to bout by prep) ----------------
__global__ __launch_bounds__(256) void reduce2_kernel(const unsigned short* __restrict__ hh,
    const float* __restrict__ wfc2, float* __restrict__ out) {
    __shared__ float s[256];
    int t = threadIdx.x;
    float w0 = wfc2[t*4+0], w1 = wfc2[t*4+1], w2 = wfc2[t*4+2], w3 = wfc2[t*4+3];
    float local = 0.f;
    for (int i = blockIdx.x; i < N_NODES; i += gridDim.x) {
        ushort4 hv = *(const ushort4*)(hh + (size_t)i*D_FF + t*4);
        local += b2f(hv.x)*w0 + b2f(hv.y)*w1 + b2f(hv.z)*w2 + b2f(hv.w)*w3;
    }
    s[t] = local; __syncthreads();
    for (int off = 128; off > 0; off >>= 1) {
        if (t < off) s[t] += s[t+off];
        __syncthreads();
    }
    if (t == 0) atomicAdd(out, s[0] * (1.0f/(float)N_NODES));
}

extern "C" void kernel_launch(void* const* d_in, const int* in_sizes, int n_in,
                              void* d_out, int out_size, void* d_ws, size_t ws_size,
                              hipStream_t stream) {
    (void)in_sizes; (void)n_in; (void)out_size; (void)ws_size;
    const float* r    = (const float*)d_in[0];
    const int*   an   = (const int*)  d_in[1];
    const int*   src  = (const int*)  d_in[2];
    const float* emb  = (const float*)d_in[6];
    const float* Wsrc = (const float*)d_in[7];
    const float* bsrc = (const float*)d_in[8];
    const float* Wdst = (const float*)d_in[9];
    const float* bdst = (const float*)d_in[10];
    const float* Wedge= (const float*)d_in[11];
    const float* bedge= (const float*)d_in[12];
    const float* attn = (const float*)d_in[13];
    const float* W1   = (const float*)d_in[14];
    const float* b1   = (const float*)d_in[15];
    const float* W2   = (const float*)d_in[16];
    const float* b2   = (const float*)d_in[17];
    const float* Wfc  = (const float*)d_in[18];
    const float* bfc  = (const float*)d_in[19];

    char* ws = (char*)d_ws;
    float* d_d              = (float*)(ws);                    // 384000 B
    float* d_rhat           = (float*)(ws + 384000);           // 1536000 B
    unsigned short* wbf     = (unsigned short*)(ws + 1920000); // 2260992 B
    unsigned short* d_x     = (unsigned short*)(ws + 4180992); // 3072000 B
    unsigned short* d_xjxi  = (unsigned short*)(ws + 7252992); // 1536000 B
    unsigned short* d_eproj = (unsigned short*)(ws + 8788992); // 36864000 B
    unsigned short* d_xn    = (unsigned short*)(ws + 45652992);// 768000 B
    unsigned short* d_h     = (unsigned short*)(ws + 46420992);// 12288000 B
    unsigned short* d_wcomb = (unsigned short*)(ws + 58708992);// 524288 B
    float* d_bcomb          = (float*)(ws + 59233280);         // 1024 B
    float* d_wfc2           = (float*)(ws + 59234304);         // 4096 B
    float* out = (float*)d_out;

    unsigned short* wsrc_bf  = wbf + WSRC_OFF;
    unsigned short* wdst_bf  = wbf + WDST_OFF;
    unsigned short* wedge_bf = wbf + WEDGE_OFF;
    unsigned short* w1_bf    = wbf + W1_OFF;

    prep_kernel<<<CVT4_BLOCKS + EMB4_BLOCKS + GEOM_BLOCKS + WCOMB_BLOCKS + WFC2_BLOCKS + 1,
                  256, 0, stream>>>(
        Wsrc, bsrc, Wdst, bdst, Wedge, W1, W2, b2, Wfc, bfc,
        wbf, an, emb, d_x, r, d_d, d_rhat, d_wcomb, d_bcomb, d_wfc2, out);
    eproj_kernel<<<750, 256, 0, stream>>>(wedge_bf, bedge, d_d, d_eproj);

    // ---- layer 0 ----
    mgemm<0,1,64><<<dim3(2,94), 256, 0, stream>>>(
        d_x, 256, wsrc_bf, wdst_bf, 256,
        bsrc, bdst, d_xjxi, 128, N_NODES, 256);
    angle_kernel<<<N_NODES/2, 256, 0, stream>>>(
        d_xjxi, d_eproj, d_rhat, src, attn, d_xn);
    mgemm<1,0,64><<<dim3(16,94), 256, 0, stream>>>(
        d_xn, 64, w1_bf, (const unsigned short*)nullptr, 64,
        b1, (const float*)nullptr, d_h, D_FF, N_NODES, 64);
    // fused FFN2+proj: xjxi(1) = h @ Wcomb1^T + bcomb1
    mgemm<0,0,64><<<dim3(2,94), 256, 0, stream>>>(
        d_h, 1024, d_wcomb, (const unsigned short*)nullptr, 1024,
        d_bcomb, (const float*)nullptr, d_xjxi, 128, N_NODES, 1024);

    // ---- layer 1 ----
    angle_kernel<<<N_NODES/2, 256, 0, stream>>>(
        d_xjxi, d_eproj + 64, d_rhat, src, attn + 64, d_xn);
    mgemm<1,0,64><<<dim3(16,94), 256, 0, stream>>>(
        d_xn, 64, w1_bf + 65536, (const unsigned short*)nullptr, 64,
        b1 + 1024, (const float*)nullptr, d_h, D_FF, N_NODES, 64);
    mgemm<0,0,64><<<dim3(2,94), 256, 0, stream>>>(
        d_h, 1024, d_wcomb + 131072, (const unsigned short*)nullptr, 1024,
        d_bcomb + 128, (const float*)nullptr, d_xjxi, 128, N_NODES, 1024);

    // ---- layer 2 ----
    angle_kernel<<<N_NODES/2, 256, 0, stream>>>(
        d_xjxi, d_eproj + 128, d_rhat, src, attn + 128, d_xn);
    mgemm<1,0,64><<<dim3(16,94), 256, 0, stream>>>(
        d_xn, 64, w1_bf + 131072, (const unsigned short*)nullptr, 64,
        b1 + 2048, (const float*)nullptr, d_h, D_FF, N_NODES, 64);
    // head: out = bout + mean(h @ wfc2)
    reduce2_kernel<<<48, 256, 0, stream>>>(d_h, d_wfc2, out);
}

// Round 14
// 326.812 us; speedup vs baseline: 1.3586x; 1.0030x over previous
//
#include <hip/hip_runtime.h>

#define N_NODES 6000
#define DEG_    16
#define N_EDGES (N_NODES*DEG_)
#define D_MODEL 256
#define D_MSG   64
#define D_FF    1024

typedef __bf16 bf16x8 __attribute__((ext_vector_type(8)));
typedef float floatx4 __attribute__((ext_vector_type(4)));

__device__ __forceinline__ float silu_f(float v) {
    return v * __builtin_amdgcn_rcpf(1.0f + __expf(-v));
}
__device__ __forceinline__ float b2f(unsigned short u) {
    union { unsigned int i; float f; } v; v.i = ((unsigned int)u) << 16; return v.f;
}
__device__ __forceinline__ unsigned short f2b(float f) {
    union { float f; unsigned int i; } v; v.f = f;
    unsigned int r = (v.i + 0x7FFFu + ((v.i >> 16) & 1u)) >> 16;
    return (unsigned short)r;
}

// ---------------- fused prep: weight cvt + embed + geom + Wcomb/wfc2/bias precompute ----------------
#define WSRC_OFF 0
#define WDST_OFF 49152
#define WEDGE_OFF 98304
#define W1_OFF 147456
#define W2_OFF 344064
#define WTOTAL 1130496
#define CVT4_BLOCKS (WTOTAL/4/256)             // 1104
#define EMB4_BLOCKS (N_NODES*D_MODEL/4/256)    // 1500
#define GEOM_BLOCKS (N_EDGES/256)              // 375
#define WCOMB_BLOCKS 256                       // 2 layers x 128 rows
#define WFC2_BLOCKS 4
__global__ __launch_bounds__(256) void prep_kernel(
    const float* __restrict__ Wsrc, const float* __restrict__ bsrc,
    const float* __restrict__ Wdst, const float* __restrict__ bdst,
    const float* __restrict__ Wedge, const float* __restrict__ W1,
    const float* __restrict__ W2, const float* __restrict__ b2,
    const float* __restrict__ Wfc, const float* __restrict__ bfc,
    unsigned short* __restrict__ wbf_out,
    const int* __restrict__ an, const float* __restrict__ emb,
    unsigned short* __restrict__ x,
    const float* __restrict__ r, float* __restrict__ d, float* __restrict__ rhat,
    unsigned short* __restrict__ wcomb, float* __restrict__ bcomb,
    float* __restrict__ wfc2, float* __restrict__ out) {
    int b = blockIdx.x;
    int t = threadIdx.x;
    if (b < CVT4_BLOCKS) {
        int i = (b*256 + t) * 4;
        const float* sp;
        if      (i < WDST_OFF)  sp = Wsrc + i;
        else if (i < WEDGE_OFF) sp = Wdst + (i - WDST_OFF);
        else if (i < W1_OFF)    sp = Wedge + (i - WEDGE_OFF);
        else if (i < W2_OFF)    sp = W1 + (i - W1_OFF);
        else                    sp = W2 + (i - W2_OFF);
        float4 v = *(const float4*)sp;
        *(ushort4*)(wbf_out + i) = make_ushort4(f2b(v.x), f2b(v.y), f2b(v.z), f2b(v.w));
    } else if (b < CVT4_BLOCKS + EMB4_BLOCKS) {
        int i4 = (b - CVT4_BLOCKS)*256 + t;
        int node = i4 >> 6, c4 = i4 & 63;
        float4 v = *(const float4*)(emb + (size_t)an[node]*D_MODEL + c4*4);
        *(ushort4*)(x + (size_t)node*D_MODEL + c4*4) =
            make_ushort4(f2b(v.x), f2b(v.y), f2b(v.z), f2b(v.w));
    } else if (b < CVT4_BLOCKS + EMB4_BLOCKS + GEOM_BLOCKS) {
        int e = (b - CVT4_BLOCKS - EMB4_BLOCKS)*256 + t;
        float xx = r[e*3+0], yy = r[e*3+1], zz = r[e*3+2];
        float n = sqrtf(xx*xx + yy*yy + zz*zz);
        d[e] = n;
        float inv = 1.0f / n;
        *(float4*)(rhat + (size_t)e*4) = make_float4(xx*inv, yy*inv, zz*inv, 0.f);
    } else if (b < CVT4_BLOCKS + EMB4_BLOCKS + GEOM_BLOCKS + WCOMB_BLOCKS) {
        int wb = b - (CVT4_BLOCKS + EMB4_BLOCKS + GEOM_BLOCKS);
        int lp  = 1 + (wb >> 7);
        int row = wb & 127;
        const float* wmrow = (row < 64) ? (Wsrc + (size_t)lp*16384 + row*256)
                                        : (Wdst + (size_t)lp*16384 + (row-64)*256);
        const float* W2f = W2 + (size_t)(lp-1)*262144;
        float a0 = 0.f, a1 = 0.f, a2 = 0.f, a3 = 0.f;
        int f = t*4;
        #pragma unroll 4
        for (int c = 0; c < 256; ++c) {
            float wm = wmrow[c];
            float4 w2v = *(const float4*)(W2f + (size_t)c*1024 + f);
            a0 = fmaf(wm, w2v.x, a0);
            a1 = fmaf(wm, w2v.y, a1);
            a2 = fmaf(wm, w2v.z, a2);
            a3 = fmaf(wm, w2v.w, a3);
        }
        *(ushort4*)(wcomb + (size_t)(lp-1)*131072 + (size_t)row*1024 + f) =
            make_ushort4(f2b(a0), f2b(a1), f2b(a2), f2b(a3));
    } else if (b < CVT4_BLOCKS + EMB4_BLOCKS + GEOM_BLOCKS + WCOMB_BLOCKS + WFC2_BLOCKS) {
        int wb = b - (CVT4_BLOCKS + EMB4_BLOCKS + GEOM_BLOCKS + WCOMB_BLOCKS);
        int c = wb*256 + t;
        const float* W2f = W2 + 2*262144;
        float acc = 0.f;
        for (int k = 0; k < 256; ++k) acc += Wfc[k] * W2f[(size_t)k*1024 + c];
        wfc2[c] = acc;
    } else {
        int lp = 1 + (t >> 7);
        int row = t & 127;
        const float* b2l = b2 + (lp-1)*256;
        const float* wmrow = (row < 64) ? (Wsrc + (size_t)lp*16384 + row*256)
                                        : (Wdst + (size_t)lp*16384 + (row-64)*256);
        float acc = 0.f;
        for (int c = 0; c < 256; ++c) acc += wmrow[c] * b2l[c];
        acc += (row < 64) ? bsrc[lp*64 + row] : bdst[lp*64 + (row-64)];
        bcomb[(lp-1)*128 + row] = acc;
        if (t == 0) {
            float bo = 0.f;
            const float* b23 = b2 + 2*256;
            for (int c = 0; c < 256; ++c) bo += Wfc[c] * b23[c];
            out[0] = bo + bfc[0];
        }
    }
}

// ---------------- eproj: [E,192] = RBF(d) @ Wedge^T + bedge, coalesced epilogue ----------------
// LDS: As 128x40 + Bs 192x40 (12800 shorts) overlaid by C-stage 64x208 (13312 shorts).
#define EPITCH 40
#define ECP 208
__global__ __launch_bounds__(256) void eproj_kernel(
    const unsigned short* __restrict__ Bw,  // [192,256] bf16 (3 layers stacked)
    const float* __restrict__ bias,         // [192]
    const float* __restrict__ dvec,         // [E]
    unsigned short* __restrict__ C) {       // [E,192]
    __shared__ __align__(16) unsigned short sm[13312];
    unsigned short* As = sm;              // 128*40 = 5120
    unsigned short* Bs = sm + 5120;       // 192*40 = 7680
    unsigned short* Cs = sm;              // 64*208 = 13312 (epilogue reuse)
    const int t = threadIdx.x;
    const int w = t >> 6, lane = t & 63, lr = lane & 15, lq = lane >> 4;
    const int m0 = blockIdx.x * 128;

    int arow[2], achk[2], brow[3], bchk[3];
    #pragma unroll
    for (int it = 0; it < 2; ++it) { int i = t + it*256; arow[it] = i >> 2; achk[it] = i & 3; }
    #pragma unroll
    for (int it = 0; it < 3; ++it) { int i = t + it*256; brow[it] = i >> 2; bchk[it] = i & 3; }

    float dv[2];
    dv[0] = dvec[m0 + arow[0]];
    dv[1] = dvec[m0 + arow[1]];

    floatx4 acc[2][12] = {};
    uint4 pb[3];
    #pragma unroll
    for (int it = 0; it < 3; ++it)
        pb[it] = *(const uint4*)(Bw + (size_t)brow[it]*256 + bchk[it]*8);

    const float gamma = 31.875f;
    const float step  = 8.0f / 255.0f;
    for (int k0 = 0; k0 < 256; k0 += 32) {
        #pragma unroll
        for (int it = 0; it < 2; ++it) {
            int kb = k0 + achk[it]*8;
            unsigned short h[8];
            #pragma unroll
            for (int j = 0; j < 8; ++j) {
                float tt = dv[it] - (float)(kb+j)*step;
                h[j] = f2b(__expf(-gamma*tt*tt));
            }
            *(uint4*)(&As[arow[it]*EPITCH + achk[it]*8]) = *(uint4*)h;
        }
        #pragma unroll
        for (int it = 0; it < 3; ++it)
            *(uint4*)(&Bs[brow[it]*EPITCH + bchk[it]*8]) = pb[it];
        __syncthreads();
        if (k0 + 32 < 256) {
            #pragma unroll
            for (int it = 0; it < 3; ++it)
                pb[it] = *(const uint4*)(Bw + (size_t)brow[it]*256 + (k0+32) + bchk[it]*8);
        }
        bf16x8 af0 = *(const bf16x8*)(&As[(w*32      + lr)*EPITCH + lq*8]);
        bf16x8 af1 = *(const bf16x8*)(&As[(w*32 + 16 + lr)*EPITCH + lq*8]);
        #pragma unroll
        for (int ns = 0; ns < 12; ++ns) {
            bf16x8 b = *(const bf16x8*)(&Bs[(ns*16 + lr)*EPITCH + lq*8]);
            acc[0][ns] = __builtin_amdgcn_mfma_f32_16x16x32_bf16(af0, b, acc[0][ns], 0,0,0);
            acc[1][ns] = __builtin_amdgcn_mfma_f32_16x16x32_bf16(af1, b, acc[1][ns], 0,0,0);
        }
        __syncthreads();
    }
    // coalesced epilogue: 2 chunks of 64 rows via LDS transpose
    #pragma unroll
    for (int chunk = 0; chunk < 2; ++chunk) {
        if ((w >> 1) == chunk) {          // waves owning these rows stage them
            int wl = w & 1;
            #pragma unroll
            for (int ns = 0; ns < 12; ++ns) {
                int bc = ns*16 + lr;
                float bv = bias[bc];
                #pragma unroll
                for (int fc = 0; fc < 2; ++fc) {
                    #pragma unroll
                    for (int rg = 0; rg < 4; ++rg) {
                        int lrow = wl*32 + fc*16 + lq*4 + rg;
                        Cs[lrow*ECP + bc] = f2b(acc[fc][ns][rg] + bv);
                    }
                }
            }
        }
        __syncthreads();
        #pragma unroll
        for (int it = 0; it < 6; ++it) {  // 64 rows x 24 uint4
            int i = t + it*256;
            int row = i / 24;
            int c = i - row*24;
            *(uint4*)(C + (size_t)(m0 + chunk*64 + row)*192 + c*8) =
                *(const uint4*)(Cs + row*ECP + c*8);
        }
        __syncthreads();
    }
}

// ---------------- MFMA bf16 GEMM (TM=64), pipelined staging + coalesced epilogue ----------------
#define APITCH 40
#define MCP 80
template<int ACT, int DUALB>
__global__ __launch_bounds__(256) void mgemm(
    const unsigned short* __restrict__ A, int lda,
    const unsigned short* __restrict__ B1, const unsigned short* __restrict__ B2, int ldb,
    const float* __restrict__ bias1, const float* __restrict__ bias2,
    unsigned short* __restrict__ C, int ldc, int M, int K) {
    __shared__ __align__(16) unsigned short sm[5120];
    unsigned short* As = sm;          // 64*40
    unsigned short* Bs = sm + 2560;   // 64*40
    unsigned short* Cs = sm;          // 64*80 epilogue reuse
    const int t = threadIdx.x;
    const int w = t >> 6;
    const int lane = t & 63;
    const int lr = lane & 15;
    const int lq = lane >> 4;
    const int n0 = blockIdx.x * 64;
    const int m0 = blockIdx.y * 64;
    const unsigned short* B = B1;
    const float* bias = bias1;
    if (DUALB && blockIdx.x == 1) { B = B2; bias = bias2; }
    const unsigned short* Brow = DUALB ? B : (B + (size_t)n0*ldb);

    const int arow = t >> 2, achk = t & 3;

    floatx4 acc[4] = {};
    uint4 pa, pb;

    {
        int gm = m0 + arow;
        pa = (gm < M) ? *(const uint4*)(A + (size_t)gm*lda + achk*8) : make_uint4(0,0,0,0);
    }
    pb = *(const uint4*)(Brow + (size_t)arow*ldb + achk*8);

    for (int k0 = 0; k0 < K; k0 += 32) {
        *(uint4*)(&As[arow*APITCH + achk*8]) = pa;
        *(uint4*)(&Bs[arow*APITCH + achk*8]) = pb;
        __syncthreads();
        if (k0 + 32 < K) {
            int kn = k0 + 32;
            int gm = m0 + arow;
            pa = (gm < M) ? *(const uint4*)(A + (size_t)gm*lda + kn + achk*8) : make_uint4(0,0,0,0);
            pb = *(const uint4*)(Brow + (size_t)arow*ldb + kn + achk*8);
        }
        bf16x8 af, bfr[4];
        af = *(const bf16x8*)(&As[(w*16 + lr)*APITCH + lq*8]);
        #pragma unroll
        for (int ns = 0; ns < 4; ++ns)
            bfr[ns] = *(const bf16x8*)(&Bs[(ns*16 + lr)*APITCH + lq*8]);
        #pragma unroll
        for (int ns = 0; ns < 4; ++ns)
            acc[ns] = __builtin_amdgcn_mfma_f32_16x16x32_bf16(af, bfr[ns], acc[ns], 0,0,0);
        __syncthreads();
    }
    // stage C tile in LDS (bf16), then coalesced uint4 store
    #pragma unroll
    for (int ns = 0; ns < 4; ++ns) {
        int bc = ns*16 + lr;
        float bv = bias[DUALB ? bc : (n0 + bc)];
        #pragma unroll
        for (int rg = 0; rg < 4; ++rg) {
            int lrow = w*16 + lq*4 + rg;
            float v = acc[ns][rg] + bv;
            if (ACT) v = silu_f(v);
            Cs[lrow*MCP + bc] = f2b(v);
        }
    }
    __syncthreads();
    #pragma unroll
    for (int it = 0; it < 2; ++it) {      // 64 rows x 8 uint4
        int i = t + it*256;
        int row = i >> 3, c8 = i & 7;
        int gm = m0 + row;
        if (gm < M)
            *(uint4*)(C + (size_t)gm*ldc + n0 + c8*8) = *(const uint4*)(Cs + row*MCP + c8*8);
    }
}

// ---------------- angle attention, TWO nodes per block ----------------
__global__ __launch_bounds__(256) void angle_kernel(
    const unsigned short* __restrict__ xjxi,
    const unsigned short* __restrict__ eproj,
    const float* __restrict__ rhat,
    const int*   __restrict__ src,
    const float* __restrict__ attn,
    unsigned short* __restrict__ xn) {
    __shared__ __align__(16) float s_xij[2][16][68];
    __shared__ float s_rhat[2][16][4];
    __shared__ float s_logit[2][16][17];
    __shared__ float s_e[2][16][17];
    __shared__ float s_m[2][16], s_zi[2][16];
    __shared__ float s_w[2][16];
    const int t = threadIdx.x;
    const int h = t >> 7, tt = t & 127;
    const int node = blockIdx.x*2 + h;

    if (tt < 16) {
        float4 rv = *(const float4*)(rhat + (size_t)(node*DEG_ + tt)*4);
        s_rhat[h][tt][0] = rv.x; s_rhat[h][tt][1] = rv.y; s_rhat[h][tt][2] = rv.z; s_rhat[h][tt][3] = 0.f;
        s_e[h][tt][tt] = 0.f;
    }
    {
        int p = tt >> 3, c8 = tt & 7;
        int e = node*DEG_ + p;
        int se = src[e];
        uint4 aj = *(const uint4*)(xjxi + (size_t)se*128 + c8*8);
        uint4 ai = *(const uint4*)(xjxi + (size_t)node*128 + 64 + c8*8);
        uint4 ae = *(const uint4*)(eproj + (size_t)e*192 + c8*8);
        const unsigned short* pj = (const unsigned short*)&aj;
        const unsigned short* pi = (const unsigned short*)&ai;
        const unsigned short* pe = (const unsigned short*)&ae;
        #pragma unroll
        for (int j = 0; j < 8; ++j)
            s_xij[h][p][c8*8 + j] = b2f(pj[j]) + b2f(pi[j]) + b2f(pe[j]);
    }
    __syncthreads();
    int pp = 0, qq = 0;
    float lg = 0.f;
    if (tt < 120) {
        pp = (int)((1.0f + sqrtf(8.0f*(float)tt + 1.0f)) * 0.5f);
        qq = tt - ((pp*(pp-1)) >> 1);
        float c = s_rhat[h][pp][0]*s_rhat[h][qq][0] + s_rhat[h][pp][1]*s_rhat[h][qq][1]
                + s_rhat[h][pp][2]*s_rhat[h][qq][2];
        c = fminf(fmaxf(c, -0.999999f), 0.999999f);
        float c2  = 2.0f * c;
        float tk0 = 1.0f;
        float tk1 = c;
        float acc = 0.f;
        const float* xp = &s_xij[h][pp][0];
        const float* xq = &s_xij[h][qq][0];
        #pragma unroll
        for (int k0 = 0; k0 < 64; k0 += 4) {
            float4 xp4 = *(const float4*)(xp + k0);
            float4 xq4 = *(const float4*)(xq + k0);
            float a0 = attn[k0+0], a1 = attn[k0+1], a2 = attn[k0+2], a3 = attn[k0+3];
            float v0 = tk0 + xp4.x + xq4.x;
            acc = fmaf(a0, silu_f(v0), acc);
            { float tn2 = c2*tk1 - tk0; tk0 = tk1; tk1 = tn2; }
            float v1 = tk0 + xp4.y + xq4.y;
            acc = fmaf(a1, silu_f(v1), acc);
            { float tn2 = c2*tk1 - tk0; tk0 = tk1; tk1 = tn2; }
            float v2 = tk0 + xp4.z + xq4.z;
            acc = fmaf(a2, silu_f(v2), acc);
            { float tn2 = c2*tk1 - tk0; tk0 = tk1; tk1 = tn2; }
            float v3 = tk0 + xp4.w + xq4.w;
            acc = fmaf(a3, silu_f(v3), acc);
            { float tn2 = c2*tk1 - tk0; tk0 = tk1; tk1 = tn2; }
        }
        lg = acc;
        s_logit[h][pp][qq] = acc;
        s_logit[h][qq][pp] = acc;
    }
    __syncthreads();
    if (tt < 16) {
        int q = tt;
        float mx = -1e30f;
        #pragma unroll
        for (int p = 0; p < 16; ++p) if (p != q) mx = fmaxf(mx, s_logit[h][p][q]);
        s_m[h][q] = mx;
    }
    __syncthreads();
    if (tt < 120) {
        s_e[h][pp][qq] = __expf(lg - s_m[h][qq]);
        s_e[h][qq][pp] = __expf(lg - s_m[h][pp]);
    }
    __syncthreads();
    if (tt < 16) {
        int q = tt;
        float z = 0.f;
        #pragma unroll
        for (int p = 0; p < 16; ++p) z += s_e[h][p][q];
        s_zi[h][q] = __builtin_amdgcn_rcpf(z);
    }
    __syncthreads();
    if (tt < 16) {
        int p = tt;
        float sw = 0.f;
        #pragma unroll
        for (int q = 0; q < 16; ++q) sw += s_e[h][p][q] * s_zi[h][q];
        s_w[h][p] = sw;
    }
    __syncthreads();
    if (tt < 64) {
        float acc = 0.f;
        #pragma unroll
        for (int p = 0; p < 16; ++p) acc += s_w[h][p] * s_xij[h][p][tt];
        xn[(size_t)node*64 + tt] = f2b(acc);
    }
}

// ---------------- final: out += mean_i (h3[i] . wfc2) ----------------
__global__ __launch_bounds__(256) void reduce2_kernel(const unsigned short* __restrict__ hh,
    const float* __restrict__ wfc2, float* __restrict__ out) {
    __shared__ float s[256];
    int t = threadIdx.x;
    float w0 = wfc2[t*4+0], w1 = wfc2[t*4+1], w2 = wfc2[t*4+2], w3 = wfc2[t*4+3];
    float local = 0.f;
    for (int i = blockIdx.x; i < N_NODES; i += gridDim.x) {
        ushort4 hv = *(const ushort4*)(hh + (size_t)i*D_FF + t*4);
        local += b2f(hv.x)*w0 + b2f(hv.y)*w1 + b2f(hv.z)*w2 + b2f(hv.w)*w3;
    }
    s[t] = local; __syncthreads();
    for (int off = 128; off > 0; off >>= 1) {
        if (t < off) s[t] += s[t+off];
        __syncthreads();
    }
    if (t == 0) atomicAdd(out, s[0] * (1.0f/(float)N_NODES));
}

extern "C" void kernel_launch(void* const* d_in, const int* in_sizes, int n_in,
                              void* d_out, int out_size, void* d_ws, size_t ws_size,
                              hipStream_t stream) {
    (void)in_sizes; (void)n_in; (void)out_size; (void)ws_size;
    const float* r    = (const float*)d_in[0];
    const int*   an   = (const int*)  d_in[1];
    const int*   src  = (const int*)  d_in[2];
    const float* emb  = (const float*)d_in[6];
    const float* Wsrc = (const float*)d_in[7];
    const float* bsrc = (const float*)d_in[8];
    const float* Wdst = (const float*)d_in[9];
    const float* bdst = (const float*)d_in[10];
    const float* Wedge= (const float*)d_in[11];
    const float* bedge= (const float*)d_in[12];
    const float* attn = (const float*)d_in[13];
    const float* W1   = (const float*)d_in[14];
    const float* b1   = (const float*)d_in[15];
    const float* W2   = (const float*)d_in[16];
    const float* b2   = (const float*)d_in[17];
    const float* Wfc  = (const float*)d_in[18];
    const float* bfc  = (const float*)d_in[19];

    char* ws = (char*)d_ws;
    float* d_d              = (float*)(ws);                    // 384000 B
    float* d_rhat           = (float*)(ws + 384000);           // 1536000 B
    unsigned short* wbf     = (unsigned short*)(ws + 1920000); // 2260992 B
    unsigned short* d_x     = (unsigned short*)(ws + 4180992); // 3072000 B
    unsigned short* d_xjxi  = (unsigned short*)(ws + 7252992); // 1536000 B
    unsigned short* d_eproj = (unsigned short*)(ws + 8788992); // 36864000 B
    unsigned short* d_xn    = (unsigned short*)(ws + 45652992);// 768000 B
    unsigned short* d_h     = (unsigned short*)(ws + 46420992);// 12288000 B
    unsigned short* d_wcomb = (unsigned short*)(ws + 58708992);// 524288 B
    float* d_bcomb          = (float*)(ws + 59233280);         // 1024 B
    float* d_wfc2           = (float*)(ws + 59234304);         // 4096 B
    float* out = (float*)d_out;

    unsigned short* wsrc_bf  = wbf + WSRC_OFF;
    unsigned short* wdst_bf  = wbf + WDST_OFF;
    unsigned short* wedge_bf = wbf + WEDGE_OFF;
    unsigned short* w1_bf    = wbf + W1_OFF;

    prep_kernel<<<CVT4_BLOCKS + EMB4_BLOCKS + GEOM_BLOCKS + WCOMB_BLOCKS + WFC2_BLOCKS + 1,
                  256, 0, stream>>>(
        Wsrc, bsrc, Wdst, bdst, Wedge, W1, W2, b2, Wfc, bfc,
        wbf, an, emb, d_x, r, d_d, d_rhat, d_wcomb, d_bcomb, d_wfc2, out);
    eproj_kernel<<<750, 256, 0, stream>>>(wedge_bf, bedge, d_d, d_eproj);

    // ---- layer 0 ----
    mgemm<0,1><<<dim3(2,94), 256, 0, stream>>>(
        d_x, 256, wsrc_bf, wdst_bf, 256,
        bsrc, bdst, d_xjxi, 128, N_NODES, 256);
    angle_kernel<<<N_NODES/2, 256, 0, stream>>>(
        d_xjxi, d_eproj, d_rhat, src, attn, d_xn);
    mgemm<1,0><<<dim3(16,94), 256, 0, stream>>>(
        d_xn, 64, w1_bf, (const unsigned short*)nullptr, 64,
        b1, (const float*)nullptr, d_h, D_FF, N_NODES, 64);
    mgemm<0,0><<<dim3(2,94), 256, 0, stream>>>(
        d_h, 1024, d_wcomb, (const unsigned short*)nullptr, 1024,
        d_bcomb, (const float*)nullptr, d_xjxi, 128, N_NODES, 1024);

    // ---- layer 1 ----
    angle_kernel<<<N_NODES/2, 256, 0, stream>>>(
        d_xjxi, d_eproj + 64, d_rhat, src, attn + 64, d_xn);
    mgemm<1,0><<<dim3(16,94), 256, 0, stream>>>(
        d_xn, 64, w1_bf + 65536, (const unsigned short*)nullptr, 64,
        b1 + 1024, (const float*)nullptr, d_h, D_FF, N_NODES, 64);
    mgemm<0,0><<<dim3(2,94), 256, 0, stream>>>(
        d_h, 1024, d_wcomb + 131072, (const unsigned short*)nullptr, 1024,
        d_bcomb + 128, (const float*)nullptr, d_xjxi, 128, N_NODES, 1024);

    // ---- layer 2 ----
    angle_kernel<<<N_NODES/2, 256, 0, stream>>>(
        d_xjxi, d_eproj + 128, d_rhat, src, attn + 128, d_xn);
    mgemm<1,0><<<dim3(16,94), 256, 0, stream>>>(
        d_xn, 64, w1_bf + 131072, (const unsigned short*)nullptr, 64,
        b1 + 2048, (const float*)nullptr, d_h, D_FF, N_NODES, 64);
    reduce2_kernel<<<48, 256, 0, stream>>>(d_h, d_wfc2, out);
}

// Round 15
// 303.634 us; speedup vs baseline: 1.4623x; 1.0763x over previous
//
#include <hip/hip_runtime.h>

#define N_NODES 6000
#define DEG_    16
#define N_EDGES (N_NODES*DEG_)
#define D_MODEL 256
#define D_MSG   64
#define D_FF    1024

typedef __bf16 bf16x8 __attribute__((ext_vector_type(8)));
typedef float floatx4 __attribute__((ext_vector_type(4)));

__device__ __forceinline__ float silu_f(float v) {
    return v * __builtin_amdgcn_rcpf(1.0f + __expf(-v));
}
__device__ __forceinline__ float b2f(unsigned short u) {
    union { unsigned int i; float f; } v; v.i = ((unsigned int)u) << 16; return v.f;
}
__device__ __forceinline__ unsigned short f2b(float f) {
    union { float f; unsigned int i; } v; v.f = f;
    unsigned int r = (v.i + 0x7FFFu + ((v.i >> 16) & 1u)) >> 16;
    return (unsigned short)r;
}

// ---------------- fused prep: weight cvt + embed + geom + Wcomb/wfc2/bias precompute ----------------
#define WSRC_OFF 0
#define WDST_OFF 49152
#define WEDGE_OFF 98304
#define W1_OFF 147456
#define W2_OFF 344064
#define WTOTAL 1130496
#define CVT4_BLOCKS (WTOTAL/4/256)             // 1104
#define EMB4_BLOCKS (N_NODES*D_MODEL/4/256)    // 1500
#define GEOM_BLOCKS (N_EDGES/256)              // 375
#define WCOMB_BLOCKS 256                       // 2 layers x 128 rows
#define WFC2_BLOCKS 4
__global__ __launch_bounds__(256) void prep_kernel(
    const float* __restrict__ Wsrc, const float* __restrict__ bsrc,
    const float* __restrict__ Wdst, const float* __restrict__ bdst,
    const float* __restrict__ Wedge, const float* __restrict__ W1,
    const float* __restrict__ W2, const float* __restrict__ b2,
    const float* __restrict__ Wfc, const float* __restrict__ bfc,
    unsigned short* __restrict__ wbf_out,
    const int* __restrict__ an, const float* __restrict__ emb,
    unsigned short* __restrict__ x,
    const float* __restrict__ r, float* __restrict__ d, float* __restrict__ rhat,
    unsigned short* __restrict__ wcomb, float* __restrict__ bcomb,
    float* __restrict__ wfc2, float* __restrict__ out) {
    int b = blockIdx.x;
    int t = threadIdx.x;
    if (b < CVT4_BLOCKS) {
        int i = (b*256 + t) * 4;
        const float* sp;
        if      (i < WDST_OFF)  sp = Wsrc + i;
        else if (i < WEDGE_OFF) sp = Wdst + (i - WDST_OFF);
        else if (i < W1_OFF)    sp = Wedge + (i - WEDGE_OFF);
        else if (i < W2_OFF)    sp = W1 + (i - W1_OFF);
        else                    sp = W2 + (i - W2_OFF);
        float4 v = *(const float4*)sp;
        *(ushort4*)(wbf_out + i) = make_ushort4(f2b(v.x), f2b(v.y), f2b(v.z), f2b(v.w));
    } else if (b < CVT4_BLOCKS + EMB4_BLOCKS) {
        int i4 = (b - CVT4_BLOCKS)*256 + t;
        int node = i4 >> 6, c4 = i4 & 63;
        float4 v = *(const float4*)(emb + (size_t)an[node]*D_MODEL + c4*4);
        *(ushort4*)(x + (size_t)node*D_MODEL + c4*4) =
            make_ushort4(f2b(v.x), f2b(v.y), f2b(v.z), f2b(v.w));
    } else if (b < CVT4_BLOCKS + EMB4_BLOCKS + GEOM_BLOCKS) {
        int e = (b - CVT4_BLOCKS - EMB4_BLOCKS)*256 + t;
        float xx = r[e*3+0], yy = r[e*3+1], zz = r[e*3+2];
        float n = sqrtf(xx*xx + yy*yy + zz*zz);
        d[e] = n;
        float inv = 1.0f / n;
        *(float4*)(rhat + (size_t)e*4) = make_float4(xx*inv, yy*inv, zz*inv, 0.f);
    } else if (b < CVT4_BLOCKS + EMB4_BLOCKS + GEOM_BLOCKS + WCOMB_BLOCKS) {
        int wb = b - (CVT4_BLOCKS + EMB4_BLOCKS + GEOM_BLOCKS);
        int lp  = 1 + (wb >> 7);
        int row = wb & 127;
        const float* wmrow = (row < 64) ? (Wsrc + (size_t)lp*16384 + row*256)
                                        : (Wdst + (size_t)lp*16384 + (row-64)*256);
        const float* W2f = W2 + (size_t)(lp-1)*262144;
        float a0 = 0.f, a1 = 0.f, a2 = 0.f, a3 = 0.f;
        int f = t*4;
        #pragma unroll 4
        for (int c = 0; c < 256; ++c) {
            float wm = wmrow[c];
            float4 w2v = *(const float4*)(W2f + (size_t)c*1024 + f);
            a0 = fmaf(wm, w2v.x, a0);
            a1 = fmaf(wm, w2v.y, a1);
            a2 = fmaf(wm, w2v.z, a2);
            a3 = fmaf(wm, w2v.w, a3);
        }
        *(ushort4*)(wcomb + (size_t)(lp-1)*131072 + (size_t)row*1024 + f) =
            make_ushort4(f2b(a0), f2b(a1), f2b(a2), f2b(a3));
    } else if (b < CVT4_BLOCKS + EMB4_BLOCKS + GEOM_BLOCKS + WCOMB_BLOCKS + WFC2_BLOCKS) {
        int wb = b - (CVT4_BLOCKS + EMB4_BLOCKS + GEOM_BLOCKS + WCOMB_BLOCKS);
        int c = wb*256 + t;
        const float* W2f = W2 + 2*262144;
        float acc = 0.f;
        for (int k = 0; k < 256; ++k) acc += Wfc[k] * W2f[(size_t)k*1024 + c];
        wfc2[c] = acc;
    } else {
        int lp = 1 + (t >> 7);
        int row = t & 127;
        const float* b2l = b2 + (lp-1)*256;
        const float* wmrow = (row < 64) ? (Wsrc + (size_t)lp*16384 + row*256)
                                        : (Wdst + (size_t)lp*16384 + (row-64)*256);
        float acc = 0.f;
        for (int c = 0; c < 256; ++c) acc += wmrow[c] * b2l[c];
        acc += (row < 64) ? bsrc[lp*64 + row] : bdst[lp*64 + (row-64)];
        bcomb[(lp-1)*128 + row] = acc;
        if (t == 0) {
            float bo = 0.f;
            const float* b23 = b2 + 2*256;
            for (int c = 0; c < 256; ++c) bo += Wfc[c] * b23[c];
            out[0] = bo + bfc[0];
        }
    }
}

// ---------------- eproj: [E,192] = RBF(d) @ Wedge^T + bedge, TM=64 (grid 1500) ----------------
// Lower VGPR (acc 48) + smaller tile -> 2-3 blocks/CU co-residency for latency hiding.
#define EPITCH 40
#define ECP 200
__global__ __launch_bounds__(256) void eproj_kernel(
    const unsigned short* __restrict__ Bw,  // [192,256] bf16 (3 layers stacked)
    const float* __restrict__ bias,         // [192]
    const float* __restrict__ dvec,         // [E]
    unsigned short* __restrict__ C) {       // [E,192]
    __shared__ __align__(16) unsigned short sm[12800];
    unsigned short* As = sm;              // 64*40 = 2560
    unsigned short* Bs = sm + 2560;       // 192*40 = 7680  (total 10240)
    unsigned short* Cs = sm;              // 64*200 = 12800 (epilogue reuse)
    const int t = threadIdx.x;
    const int w = t >> 6, lane = t & 63, lr = lane & 15, lq = lane >> 4;
    const int m0 = blockIdx.x * 64;

    const int arow = t >> 2, achk = t & 3;
    int brow[3], bchk[3];
    #pragma unroll
    for (int it = 0; it < 3; ++it) { int i = t + it*256; brow[it] = i >> 2; bchk[it] = i & 3; }

    float dv = dvec[m0 + arow];

    floatx4 acc[12] = {};
    uint4 pb[3];
    #pragma unroll
    for (int it = 0; it < 3; ++it)
        pb[it] = *(const uint4*)(Bw + (size_t)brow[it]*256 + bchk[it]*8);

    const float gamma = 31.875f;
    const float step  = 8.0f / 255.0f;
    for (int k0 = 0; k0 < 256; k0 += 32) {
        {
            int kb = k0 + achk*8;
            unsigned short h[8];
            #pragma unroll
            for (int j = 0; j < 8; ++j) {
                float tt = dv - (float)(kb+j)*step;
                h[j] = f2b(__expf(-gamma*tt*tt));
            }
            *(uint4*)(&As[arow*EPITCH + achk*8]) = *(uint4*)h;
        }
        #pragma unroll
        for (int it = 0; it < 3; ++it)
            *(uint4*)(&Bs[brow[it]*EPITCH + bchk[it]*8]) = pb[it];
        __syncthreads();
        if (k0 + 32 < 256) {
            #pragma unroll
            for (int it = 0; it < 3; ++it)
                pb[it] = *(const uint4*)(Bw + (size_t)brow[it]*256 + (k0+32) + bchk[it]*8);
        }
        bf16x8 af = *(const bf16x8*)(&As[(w*16 + lr)*EPITCH + lq*8]);
        #pragma unroll
        for (int ns = 0; ns < 12; ++ns) {
            bf16x8 b = *(const bf16x8*)(&Bs[(ns*16 + lr)*EPITCH + lq*8]);
            acc[ns] = __builtin_amdgcn_mfma_f32_16x16x32_bf16(af, b, acc[ns], 0,0,0);
        }
        __syncthreads();
    }
    // coalesced epilogue via LDS
    #pragma unroll
    for (int ns = 0; ns < 12; ++ns) {
        int bc = ns*16 + lr;
        float bv = bias[bc];
        #pragma unroll
        for (int rg = 0; rg < 4; ++rg) {
            int lrow = w*16 + lq*4 + rg;
            Cs[lrow*ECP + bc] = f2b(acc[ns][rg] + bv);
        }
    }
    __syncthreads();
    #pragma unroll
    for (int it = 0; it < 6; ++it) {  // 64 rows x 24 uint4
        int i = t + it*256;
        int row = i / 24;
        int c = i - row*24;
        *(uint4*)(C + (size_t)(m0 + row)*192 + c*8) = *(const uint4*)(Cs + row*ECP + c*8);
    }
}

// ---------------- MFMA bf16 GEMM (TM=64), pipelined staging + coalesced epilogue ----------------
#define APITCH 40
#define MCP 72
template<int ACT, int DUALB>
__global__ __launch_bounds__(256) void mgemm(
    const unsigned short* __restrict__ A, int lda,
    const unsigned short* __restrict__ B1, const unsigned short* __restrict__ B2, int ldb,
    const float* __restrict__ bias1, const float* __restrict__ bias2,
    unsigned short* __restrict__ C, int ldc, int M, int K) {
    __shared__ __align__(16) unsigned short sm[5120];
    unsigned short* As = sm;          // 64*40
    unsigned short* Bs = sm + 2560;   // 64*40
    unsigned short* Cs = sm;          // 64*72 epilogue reuse (4608)
    const int t = threadIdx.x;
    const int w = t >> 6;
    const int lane = t & 63;
    const int lr = lane & 15;
    const int lq = lane >> 4;
    const int n0 = blockIdx.x * 64;
    const int m0 = blockIdx.y * 64;
    const unsigned short* B = B1;
    const float* bias = bias1;
    if (DUALB && blockIdx.x == 1) { B = B2; bias = bias2; }
    const unsigned short* Brow = DUALB ? B : (B + (size_t)n0*ldb);

    const int arow = t >> 2, achk = t & 3;

    floatx4 acc[4] = {};
    uint4 pa, pb;

    {
        int gm = m0 + arow;
        pa = (gm < M) ? *(const uint4*)(A + (size_t)gm*lda + achk*8) : make_uint4(0,0,0,0);
    }
    pb = *(const uint4*)(Brow + (size_t)arow*ldb + achk*8);

    for (int k0 = 0; k0 < K; k0 += 32) {
        *(uint4*)(&As[arow*APITCH + achk*8]) = pa;
        *(uint4*)(&Bs[arow*APITCH + achk*8]) = pb;
        __syncthreads();
        if (k0 + 32 < K) {
            int kn = k0 + 32;
            int gm = m0 + arow;
            pa = (gm < M) ? *(const uint4*)(A + (size_t)gm*lda + kn + achk*8) : make_uint4(0,0,0,0);
            pb = *(const uint4*)(Brow + (size_t)arow*ldb + kn + achk*8);
        }
        bf16x8 af, bfr[4];
        af = *(const bf16x8*)(&As[(w*16 + lr)*APITCH + lq*8]);
        #pragma unroll
        for (int ns = 0; ns < 4; ++ns)
            bfr[ns] = *(const bf16x8*)(&Bs[(ns*16 + lr)*APITCH + lq*8]);
        #pragma unroll
        for (int ns = 0; ns < 4; ++ns)
            acc[ns] = __builtin_amdgcn_mfma_f32_16x16x32_bf16(af, bfr[ns], acc[ns], 0,0,0);
        __syncthreads();
    }
    #pragma unroll
    for (int ns = 0; ns < 4; ++ns) {
        int bc = ns*16 + lr;
        float bv = bias[DUALB ? bc : (n0 + bc)];
        #pragma unroll
        for (int rg = 0; rg < 4; ++rg) {
            int lrow = w*16 + lq*4 + rg;
            float v = acc[ns][rg] + bv;
            if (ACT) v = silu_f(v);
            Cs[lrow*MCP + bc] = f2b(v);
        }
    }
    __syncthreads();
    #pragma unroll
    for (int it = 0; it < 2; ++it) {      // 64 rows x 8 uint4
        int i = t + it*256;
        int row = i >> 3, c8 = i & 7;
        int gm = m0 + row;
        if (gm < M)
            *(uint4*)(C + (size_t)gm*ldc + n0 + c8*8) = *(const uint4*)(Cs + row*MCP + c8*8);
    }
}

// ---------------- angle attention, TWO nodes per block ----------------
__global__ __launch_bounds__(256) void angle_kernel(
    const unsigned short* __restrict__ xjxi,
    const unsigned short* __restrict__ eproj,
    const float* __restrict__ rhat,
    const int*   __restrict__ src,
    const float* __restrict__ attn,
    unsigned short* __restrict__ xn) {
    __shared__ __align__(16) float s_xij[2][16][68];
    __shared__ float s_rhat[2][16][4];
    __shared__ float s_logit[2][16][17];
    __shared__ float s_e[2][16][17];
    __shared__ float s_m[2][16], s_zi[2][16];
    __shared__ float s_w[2][16];
    const int t = threadIdx.x;
    const int h = t >> 7, tt = t & 127;
    const int node = blockIdx.x*2 + h;

    if (tt < 16) {
        float4 rv = *(const float4*)(rhat + (size_t)(node*DEG_ + tt)*4);
        s_rhat[h][tt][0] = rv.x; s_rhat[h][tt][1] = rv.y; s_rhat[h][tt][2] = rv.z; s_rhat[h][tt][3] = 0.f;
        s_e[h][tt][tt] = 0.f;
    }
    {
        int p = tt >> 3, c8 = tt & 7;
        int e = node*DEG_ + p;
        int se = src[e];
        uint4 aj = *(const uint4*)(xjxi + (size_t)se*128 + c8*8);
        uint4 ai = *(const uint4*)(xjxi + (size_t)node*128 + 64 + c8*8);
        uint4 ae = *(const uint4*)(eproj + (size_t)e*192 + c8*8);
        const unsigned short* pj = (const unsigned short*)&aj;
        const unsigned short* pi = (const unsigned short*)&ai;
        const unsigned short* pe = (const unsigned short*)&ae;
        #pragma unroll
        for (int j = 0; j < 8; ++j)
            s_xij[h][p][c8*8 + j] = b2f(pj[j]) + b2f(pi[j]) + b2f(pe[j]);
    }
    __syncthreads();
    int pp = 0, qq = 0;
    float lg = 0.f;
    if (tt < 120) {
        pp = (int)((1.0f + sqrtf(8.0f*(float)tt + 1.0f)) * 0.5f);
        qq = tt - ((pp*(pp-1)) >> 1);
        float c = s_rhat[h][pp][0]*s_rhat[h][qq][0] + s_rhat[h][pp][1]*s_rhat[h][qq][1]
                + s_rhat[h][pp][2]*s_rhat[h][qq][2];
        c = fminf(fmaxf(c, -0.999999f), 0.999999f);
        float c2  = 2.0f * c;
        float tk0 = 1.0f;
        float tk1 = c;
        float acc = 0.f;
        const float* xp = &s_xij[h][pp][0];
        const float* xq = &s_xij[h][qq][0];
        #pragma unroll
        for (int k0 = 0; k0 < 64; k0 += 4) {
            float4 xp4 = *(const float4*)(xp + k0);
            float4 xq4 = *(const float4*)(xq + k0);
            float a0 = attn[k0+0], a1 = attn[k0+1], a2 = attn[k0+2], a3 = attn[k0+3];
            float v0 = tk0 + xp4.x + xq4.x;
            acc = fmaf(a0, silu_f(v0), acc);
            { float tn2 = c2*tk1 - tk0; tk0 = tk1; tk1 = tn2; }
            float v1 = tk0 + xp4.y + xq4.y;
            acc = fmaf(a1, silu_f(v1), acc);
            { float tn2 = c2*tk1 - tk0; tk0 = tk1; tk1 = tn2; }
            float v2 = tk0 + xp4.z + xq4.z;
            acc = fmaf(a2, silu_f(v2), acc);
            { float tn2 = c2*tk1 - tk0; tk0 = tk1; tk1 = tn2; }
            float v3 = tk0 + xp4.w + xq4.w;
            acc = fmaf(a3, silu_f(v3), acc);
            { float tn2 = c2*tk1 - tk0; tk0 = tk1; tk1 = tn2; }
        }
        lg = acc;
        s_logit[h][pp][qq] = acc;
        s_logit[h][qq][pp] = acc;
    }
    __syncthreads();
    if (tt < 16) {
        int q = tt;
        float mx = -1e30f;
        #pragma unroll
        for (int p = 0; p < 16; ++p) if (p != q) mx = fmaxf(mx, s_logit[h][p][q]);
        s_m[h][q] = mx;
    }
    __syncthreads();
    if (tt < 120) {
        s_e[h][pp][qq] = __expf(lg - s_m[h][qq]);
        s_e[h][qq][pp] = __expf(lg - s_m[h][pp]);
    }
    __syncthreads();
    if (tt < 16) {
        int q = tt;
        float z = 0.f;
        #pragma unroll
        for (int p = 0; p < 16; ++p) z += s_e[h][p][q];
        s_zi[h][q] = __builtin_amdgcn_rcpf(z);
    }
    __syncthreads();
    if (tt < 16) {
        int p = tt;
        float sw = 0.f;
        #pragma unroll
        for (int q = 0; q < 16; ++q) sw += s_e[h][p][q] * s_zi[h][q];
        s_w[h][p] = sw;
    }
    __syncthreads();
    if (tt < 64) {
        float acc = 0.f;
        #pragma unroll
        for (int p = 0; p < 16; ++p) acc += s_w[h][p] * s_xij[h][p][tt];
        xn[(size_t)node*64 + tt] = f2b(acc);
    }
}

// ---------------- final: out += mean_i (h3[i] . wfc2) ----------------
__global__ __launch_bounds__(256) void reduce2_kernel(const unsigned short* __restrict__ hh,
    const float* __restrict__ wfc2, float* __restrict__ out) {
    __shared__ float s[256];
    int t = threadIdx.x;
    float w0 = wfc2[t*4+0], w1 = wfc2[t*4+1], w2 = wfc2[t*4+2], w3 = wfc2[t*4+3];
    float local = 0.f;
    for (int i = blockIdx.x; i < N_NODES; i += gridDim.x) {
        ushort4 hv = *(const ushort4*)(hh + (size_t)i*D_FF + t*4);
        local += b2f(hv.x)*w0 + b2f(hv.y)*w1 + b2f(hv.z)*w2 + b2f(hv.w)*w3;
    }
    s[t] = local; __syncthreads();
    for (int off = 128; off > 0; off >>= 1) {
        if (t < off) s[t] += s[t+off];
        __syncthreads();
    }
    if (t == 0) atomicAdd(out, s[0] * (1.0f/(float)N_NODES));
}

extern "C" void kernel_launch(void* const* d_in, const int* in_sizes, int n_in,
                              void* d_out, int out_size, void* d_ws, size_t ws_size,
                              hipStream_t stream) {
    (void)in_sizes; (void)n_in; (void)out_size; (void)ws_size;
    const float* r    = (const float*)d_in[0];
    const int*   an   = (const int*)  d_in[1];
    const int*   src  = (const int*)  d_in[2];
    const float* emb  = (const float*)d_in[6];
    const float* Wsrc = (const float*)d_in[7];
    const float* bsrc = (const float*)d_in[8];
    const float* Wdst = (const float*)d_in[9];
    const float* bdst = (const float*)d_in[10];
    const float* Wedge= (const float*)d_in[11];
    const float* bedge= (const float*)d_in[12];
    const float* attn = (const float*)d_in[13];
    const float* W1   = (const float*)d_in[14];
    const float* b1   = (const float*)d_in[15];
    const float* W2   = (const float*)d_in[16];
    const float* b2   = (const float*)d_in[17];
    const float* Wfc  = (const float*)d_in[18];
    const float* bfc  = (const float*)d_in[19];

    char* ws = (char*)d_ws;
    float* d_d              = (float*)(ws);                    // 384000 B
    float* d_rhat           = (float*)(ws + 384000);           // 1536000 B
    unsigned short* wbf     = (unsigned short*)(ws + 1920000); // 2260992 B
    unsigned short* d_x     = (unsigned short*)(ws + 4180992); // 3072000 B
    unsigned short* d_xjxi  = (unsigned short*)(ws + 7252992); // 1536000 B
    unsigned short* d_eproj = (unsigned short*)(ws + 8788992); // 36864000 B
    unsigned short* d_xn    = (unsigned short*)(ws + 45652992);// 768000 B
    unsigned short* d_h     = (unsigned short*)(ws + 46420992);// 12288000 B
    unsigned short* d_wcomb = (unsigned short*)(ws + 58708992);// 524288 B
    float* d_bcomb          = (float*)(ws + 59233280);         // 1024 B
    float* d_wfc2           = (float*)(ws + 59234304);         // 4096 B
    float* out = (float*)d_out;

    unsigned short* wsrc_bf  = wbf + WSRC_OFF;
    unsigned short* wdst_bf  = wbf + WDST_OFF;
    unsigned short* wedge_bf = wbf + WEDGE_OFF;
    unsigned short* w1_bf    = wbf + W1_OFF;

    prep_kernel<<<CVT4_BLOCKS + EMB4_BLOCKS + GEOM_BLOCKS + WCOMB_BLOCKS + WFC2_BLOCKS + 1,
                  256, 0, stream>>>(
        Wsrc, bsrc, Wdst, bdst, Wedge, W1, W2, b2, Wfc, bfc,
        wbf, an, emb, d_x, r, d_d, d_rhat, d_wcomb, d_bcomb, d_wfc2, out);
    eproj_kernel<<<1500, 256, 0, stream>>>(wedge_bf, bedge, d_d, d_eproj);

    // ---- layer 0 ----
    mgemm<0,1><<<dim3(2,94), 256, 0, stream>>>(
        d_x, 256, wsrc_bf, wdst_bf, 256,
        bsrc, bdst, d_xjxi, 128, N_NODES, 256);
    angle_kernel<<<N_NODES/2, 256, 0, stream>>>(
        d_xjxi, d_eproj, d_rhat, src, attn, d_xn);
    mgemm<1,0><<<dim3(16,94), 256, 0, stream>>>(
        d_xn, 64, w1_bf, (const unsigned short*)nullptr, 64,
        b1, (const float*)nullptr, d_h, D_FF, N_NODES, 64);
    mgemm<0,0><<<dim3(2,94), 256, 0, stream>>>(
        d_h, 1024, d_wcomb, (const unsigned short*)nullptr, 1024,
        d_bcomb, (const float*)nullptr, d_xjxi, 128, N_NODES, 1024);

    // ---- layer 1 ----
    angle_kernel<<<N_NODES/2, 256, 0, stream>>>(
        d_xjxi, d_eproj + 64, d_rhat, src, attn + 64, d_xn);
    mgemm<1,0><<<dim3(16,94), 256, 0, stream>>>(
        d_xn, 64, w1_bf + 65536, (const unsigned short*)nullptr, 64,
        b1 + 1024, (const float*)nullptr, d_h, D_FF, N_NODES, 64);
    mgemm<0,0><<<dim3(2,94), 256, 0, stream>>>(
        d_h, 1024, d_wcomb + 131072, (const unsigned short*)nullptr, 1024,
        d_bcomb + 128, (const float*)nullptr, d_xjxi, 128, N_NODES, 1024);

    // ---- layer 2 ----
    angle_kernel<<<N_NODES/2, 256, 0, stream>>>(
        d_xjxi, d_eproj + 128, d_rhat, src, attn + 128, d_xn);
    mgemm<1,0><<<dim3(16,94), 256, 0, stream>>>(
        d_xn, 64, w1_bf + 131072, (const unsigned short*)nullptr, 64,
        b1 + 2048, (const float*)nullptr, d_h, D_FF, N_NODES, 64);
    reduce2_kernel<<<400, 256, 0, stream>>>(d_h, d_wfc2, out);
}